// Round 11
// baseline (777.255 us; speedup 1.0000x reference)
//
#include <hip/hip_runtime.h>
#include <cfloat>
#include <cstdint>
#include <cstddef>

#define NROWS 8192
#define HID 256
#define NCLS 5
#define TOPK 10
#define CAP 256     // per-row candidate capacity (typ. ~20-60 used)
#define TM 128
#define TN 128
#define BK 32
#define BKS 64      // sim K-step

typedef __bf16 bf16x8 __attribute__((ext_vector_type(8)));
typedef float f32x4 __attribute__((ext_vector_type(4)));
typedef unsigned short us4 __attribute__((ext_vector_type(4)));

__device__ inline ushort f2bf(float x) {
  unsigned u = __float_as_uint(x);
  unsigned r = (u + 0x7fffu + ((u >> 16) & 1u)) >> 16;  // RNE
  return (ushort)r;
}
__device__ inline float bf2f(ushort b) { return __uint_as_float(((unsigned)b) << 16); }

// async global->LDS 16B/lane; LDS dest is wave-uniform base + lane*16
__device__ __forceinline__ void load_lds16(const void* g, void* l) {
  __builtin_amdgcn_global_load_lds(
      (const __attribute__((address_space(1))) void*)g,
      (__attribute__((address_space(3))) void*)l, 16, 0, 0);
}

// ---------------------------------------------------------------------------
// Batched encoder pack, 4-WIDE (z = modality): X -> hi/lo limb planes
// (COMPACT per-z row stride Kp[z], zero-padded past D), W -> transposed
// [HID x Kp[z]] planes. float4 loads (alignment-guarded) + ushort4 stores;
// per-element RNE math unchanged -> bit-identical values. (R7-verified:
// rest-of-pipeline -44 us vs scalar.)
// ---------------------------------------------------------------------------
__global__ __launch_bounds__(256) void packAB_kernel(const float* __restrict__ X0,
    const float* __restrict__ X1, const float* __restrict__ X2,
    const float* __restrict__ W0, const float* __restrict__ W1,
    const float* __restrict__ W2, ushort* __restrict__ Ah, ushort* __restrict__ Al,
    ushort* __restrict__ Bh, ushort* __restrict__ Bl,
    int D0, int D1, int D2, int Kp0, int Kp1, int Kp2,
    size_t aOff0, size_t aOff1, size_t aOff2,
    size_t wOff0, size_t wOff1, size_t wOff2) {
  const int z = blockIdx.y;
  const float* X = (z == 0) ? X0 : (z == 1) ? X1 : X2;
  const float* W = (z == 0) ? W0 : (z == 1) ? W1 : W2;
  const int D = (z == 0) ? D0 : (z == 1) ? D1 : D2;
  const int Kp = (z == 0) ? Kp0 : (z == 1) ? Kp1 : Kp2;
  const size_t aOff = (z == 0) ? aOff0 : (z == 1) ? aOff1 : aOff2;
  const size_t wOff = (z == 0) ? wOff0 : (z == 1) ? wOff1 : wOff2;
  const int ksh2 = (31 - __clz(Kp)) - 2;     // log2(Kp/4)
  const int id4 = blockIdx.x * 256 + threadIdx.x;
  const int aq = NROWS << ksh2;
  const int wq = HID << ksh2;
  if (id4 >= aq + wq) return;
  float x[4];
  ushort h[4], l[4];
  if (id4 < aq) {
    const int kq = id4 & ((Kp >> 2) - 1);
    const int r = id4 >> ksh2;
    const int k = kq << 2;
    const float* src = X + (size_t)r * D + k;
    if (k + 3 < D && ((((size_t)r * D + k) & 3) == 0)) {
      const float4 v = *(const float4*)src;
      x[0] = v.x; x[1] = v.y; x[2] = v.z; x[3] = v.w;
    } else {
      #pragma unroll
      for (int j = 0; j < 4; ++j) x[j] = (k + j < D) ? src[j] : 0.f;
    }
    #pragma unroll
    for (int j = 0; j < 4; ++j) { h[j] = f2bf(x[j]); l[j] = f2bf(x[j] - bf2f(h[j])); }
    const size_t o = aOff + (((size_t)r) << (ksh2 + 2)) + k;
    *(us4*)&Ah[o] = (us4){h[0], h[1], h[2], h[3]};
    *(us4*)&Al[o] = (us4){l[0], l[1], l[2], l[3]};
  } else {
    const int id2 = id4 - aq;
    const int kq = id2 & ((Kp >> 2) - 1);
    const int n = id2 >> ksh2;
    const int k = kq << 2;
    #pragma unroll
    for (int j = 0; j < 4; ++j) {
      const float xv = (k + j < D) ? W[(size_t)(k + j) * HID + n] : 0.f;
      h[j] = f2bf(xv); l[j] = f2bf(xv - bf2f(h[j]));
    }
    const size_t o = wOff + (((size_t)n) << (ksh2 + 2)) + k;
    *(us4*)&Bh[o] = (us4){h[0], h[1], h[2], h[3]};
    *(us4*)&Bl[o] = (us4){l[0], l[1], l[2], l[3]};
  }
}

// ---------------------------------------------------------------------------
// Batched GCN weight pack: W[z] [HID x HID] -> transposed limb planes.
// ---------------------------------------------------------------------------
__global__ __launch_bounds__(256) void packW_kernel(const float* __restrict__ W,
    ushort* __restrict__ Bh, ushort* __restrict__ Bl) {
  const int z = blockIdx.y;
  const int id = blockIdx.x * 256 + threadIdx.x;  // 65536 per z
  const int k = id >> 8, n = id & 255;
  const size_t wz = (size_t)z * HID * HID;
  const float x = W[wz + (size_t)k * HID + n];
  const ushort h = f2bf(x);
  Bh[wz + (size_t)n * HID + k] = h;
  Bl[wz + (size_t)n * HID + k] = f2bf(x - bf2f(h));
}

// ---------------------------------------------------------------------------
// Batched 3-segment two-limb bf16 MFMA GEMM, 128x128 tile. 4 waves (2x2),
// wave = 64x64 = acc[4][4]. Staging/fragment swizzle = proven R4 mapping.
// 2-PHASE double-buffered staging: step t issues global_load_lds for t+1
// BEFORE computing t; ONE __syncthreads per step (drain overlaps compute).
// Per-k accumulation order (hh,hl,lh) unchanged -> bit-identical results.
// ---------------------------------------------------------------------------
#define STAGE_LIMB(B, K0)                              \
    load_lds16(Ah + a0 + (K0), &AsH[B][p0 * 8]);       \
    load_lds16(Ah + a1 + (K0), &AsH[B][p1 * 8]);       \
    load_lds16(Al + a0 + (K0), &AsL[B][p0 * 8]);       \
    load_lds16(Al + a1 + (K0), &AsL[B][p1 * 8]);       \
    load_lds16(Bh + b0 + (K0), &BsH[B][p0 * 8]);       \
    load_lds16(Bh + b1 + (K0), &BsH[B][p1 * 8]);       \
    load_lds16(Bl + b0 + (K0), &BsL[B][p0 * 8]);       \
    load_lds16(Bl + b1 + (K0), &BsL[B][p1 * 8]);

template<bool BIAS, int ACT>
__global__ __launch_bounds__(256) void limbgemm_kernel(const ushort* __restrict__ Ah,
    const ushort* __restrict__ Al, const ushort* __restrict__ Bh,
    const ushort* __restrict__ Bl, const float* __restrict__ bias,
    float* __restrict__ C, int Kp0, int Kp1, int Kp2,
    size_t aOff0, size_t aOff1, size_t aOff2,
    size_t bOff0, size_t bOff1, size_t bOff2) {
  __shared__ ushort AsH[2][TM * BK], AsL[2][TM * BK], BsH[2][TM * BK], BsL[2][TM * BK];
  const int z = blockIdx.y;
  const int Kp = (z == 0) ? Kp0 : (z == 1) ? Kp1 : Kp2;
  const size_t aO = (z == 0) ? aOff0 : (z == 1) ? aOff1 : aOff2;
  const size_t bO = (z == 0) ? bOff0 : (z == 1) ? bOff1 : bOff2;
  Ah += aO; Al += aO; Bh += bO; Bl += bO;
  C += (size_t)z * NROWS * HID;
  const int tid = threadIdx.x;
  const int wave = tid >> 6, lane = tid & 63;
  // XCD swizzle: 128 blocks = 64 row-blocks x 2 col-blocks
  const int bid = blockIdx.x;
  const int xcd = bid & 7, slot = bid >> 3;      // slot 0..15
  const int bxi = slot & 1;
  const int byi = xcd * 8 + (slot >> 1);
  const int bm = byi * TM, bn = bxi * 128;
  const int wr = (wave >> 1) * 64, wc = (wave & 1) * 64;

  f32x4 acc[4][4];
  const f32x4 zero = {0.f, 0.f, 0.f, 0.f};
  #pragma unroll
  for (int i = 0; i < 4; ++i)
    #pragma unroll
    for (int j = 0; j < 4; ++j) acc[i][j] = zero;

  // staging slots (proven R4 mapping): p in {tid, tid+256}, r=p>>2,
  // kl = (p&3) ^ ((r&3) ^ ((r>>2)&1))
  const int p0 = tid, p1 = tid + 256;
  const int r0 = p0 >> 2, kl0 = (p0 & 3) ^ ((r0 & 3) ^ ((r0 >> 2) & 1));
  const int r1 = p1 >> 2, kl1 = (p1 & 3) ^ ((r1 & 3) ^ ((r1 >> 2) & 1));
  const size_t a0 = (size_t)(bm + r0) * Kp + kl0 * 8;
  const size_t a1 = (size_t)(bm + r1) * Kp + kl1 * 8;
  const size_t b0 = (size_t)(bn + r0) * Kp + kl0 * 8;
  const size_t b1 = (size_t)(bn + r1) * Kp + kl1 * 8;

  // prologue: stage k0=0 into buffer 0
  STAGE_LIMB(0, 0)
  __syncthreads();
  int cur = 0;
  for (int k0 = 0; k0 < Kp; k0 += BK) {
    if (k0 + BK < Kp) {
      STAGE_LIMB(cur ^ 1, k0 + BK)
    }
    bf16x8 ah[4], al[4], bh[4], bl[4];
    const int kg = lane >> 4;
    #pragma unroll
    for (int f = 0; f < 4; ++f) {
      const int m = wr + f * 16 + (lane & 15);
      const int sa = m * 4 + (kg ^ (m & 3) ^ ((m >> 2) & 1));
      ah[f] = *(const bf16x8*)&AsH[cur][sa * 8];
      al[f] = *(const bf16x8*)&AsL[cur][sa * 8];
      const int n = wc + f * 16 + (lane & 15);
      const int sb = n * 4 + (kg ^ (n & 3) ^ ((n >> 2) & 1));
      bh[f] = *(const bf16x8*)&BsH[cur][sb * 8];
      bl[f] = *(const bf16x8*)&BsL[cur][sb * 8];
    }
    #pragma unroll
    for (int fr = 0; fr < 4; ++fr)
      #pragma unroll
      for (int fc = 0; fc < 4; ++fc) {
        acc[fr][fc] = __builtin_amdgcn_mfma_f32_16x16x32_bf16(ah[fr], bh[fc], acc[fr][fc], 0, 0, 0);
        acc[fr][fc] = __builtin_amdgcn_mfma_f32_16x16x32_bf16(ah[fr], bl[fc], acc[fr][fc], 0, 0, 0);
        acc[fr][fc] = __builtin_amdgcn_mfma_f32_16x16x32_bf16(al[fr], bh[fc], acc[fr][fc], 0, 0, 0);
      }
    __syncthreads();
    cur ^= 1;
  }
  const int cq = lane >> 4, cc = lane & 15;
  #pragma unroll
  for (int fr = 0; fr < 4; ++fr) {
    #pragma unroll
    for (int fc = 0; fc < 4; ++fc) {
      const int rb = bm + wr + fr * 16 + cq * 4;
      const int col = bn + wc + fc * 16 + cc;
      const float bb = BIAS ? bias[z * HID + col] : 0.f;
      float* cp = C + (size_t)rb * HID + col;
      #pragma unroll
      for (int e = 0; e < 4; ++e) {
        float v = acc[fr][fc][e] + bb;
        if (ACT == 1) v = fmaxf(v, 0.f);
        cp[(size_t)e * HID] = v;
      }
    }
  }
}

// ---------------------------------------------------------------------------
// Batched coalesced BatchNorm, 3 stages.
// ---------------------------------------------------------------------------
__global__ __launch_bounds__(256) void bn_stats_kernel(const float* __restrict__ F,
    float* __restrict__ ps, float* __restrict__ ps2) {
  const int z = blockIdx.y;
  const int b = blockIdx.x, t = threadIdx.x;
  float s = 0.f, s2 = 0.f;
  const float* p = F + (size_t)z * NROWS * HID + (size_t)b * 128 * HID + t;
  for (int r = 0; r < 128; ++r) {
    const float v = p[(size_t)r * HID];
    s += v; s2 += v * v;
  }
  ps[(size_t)z * 64 * HID + b * HID + t] = s;
  ps2[(size_t)z * 64 * HID + b * HID + t] = s2;
}

__global__ __launch_bounds__(256) void bn_finalize_kernel(const float* __restrict__ ps,
    const float* __restrict__ ps2, const float* __restrict__ g,
    const float* __restrict__ b, float* __restrict__ scale, float* __restrict__ shift) {
  const int z = blockIdx.x;
  const int t = threadIdx.x;
  float s = 0.f, s2 = 0.f;
  for (int i = 0; i < 64; ++i) {
    s += ps[(size_t)z * 64 * HID + i * HID + t];
    s2 += ps2[(size_t)z * 64 * HID + i * HID + t];
  }
  const float mu = s / (float)NROWS;
  const float var = s2 / (float)NROWS - mu * mu;
  const float rstd = rsqrtf(var + 1e-5f);
  const float sc = rstd * g[z * HID + t];
  scale[z * HID + t] = sc;
  shift[z * HID + t] = b[z * HID + t] - mu * sc;
}

// ---------------------------------------------------------------------------
// Batched fused bn-apply + L2 rownorm. Emits FN, Ph (hi-limb fn), Fh/Fl.
// ---------------------------------------------------------------------------
__global__ __launch_bounds__(256) void bn_rownorm_kernel(const float* __restrict__ F,
    const float* __restrict__ scale, const float* __restrict__ shift,
    float* __restrict__ FN, ushort* __restrict__ Ph,
    ushort* __restrict__ Fh, ushort* __restrict__ Fl) {
  const int z = blockIdx.y;
  const int r = blockIdx.x, t = threadIdx.x;
  const size_t zb = (size_t)z * NROWS * HID;
  const float f = F[zb + (size_t)r * HID + t] * scale[z * HID + t] + shift[z * HID + t];
  __shared__ float sh[256];
  sh[t] = f * f;
  __syncthreads();
  for (int st = 128; st > 0; st >>= 1) {
    if (t < st) sh[t] += sh[t + st];
    __syncthreads();
  }
  const float inv = 1.0f / fmaxf(sqrtf(sh[0]), 1e-12f);
  const float fn = f * inv;
  const size_t o = zb + (size_t)r * HID + t;
  FN[o] = fn;
  Ph[o] = f2bf(fn);
  const ushort h = f2bf(f);
  Fh[o] = h;
  Fl[o] = f2bf(f - bf2f(h));
}

// ---------------------------------------------------------------------------
// Batched SYMMETRIC stripe-free sim: TRIANGULAR grid (2080/z, row-major
// decode, no dead dispatches). R6-VERIFIED config: BKS=64 single-buffer,
// 33 KB LDS, m*8+(kgb^(m&7)) swizzle — measured 118 us, 0 bank conflicts.
// (BK=32-style mapping REGRESSES: 9.58M conflicts, +25 us — R7.)
// PASS 0: per-row/per-col tile maxes -> M. PASS 1: tau-compaction both dirs.
// ---------------------------------------------------------------------------
template<int PASS>
__global__ __launch_bounds__(512) void simtile_kernel(const ushort* __restrict__ P,
    float* __restrict__ M, const float* __restrict__ tauv,
    int* __restrict__ gcnt, int* __restrict__ gidx) {
  // row-major upper-triangle decode: tlin -> (by, bx) with by <= bx < 64.
  const int tlin = blockIdx.x;
  int by = (int)(64.5f - sqrtf(4160.25f - 2.0f * (float)tlin));
  if (by < 0) by = 0;
  if (by > 63) by = 63;
  while (by > 0 && (by * 64 - (by * (by - 1)) / 2) > tlin) --by;
  while (by < 63 && ((by + 1) * 64 - ((by + 1) * by) / 2) <= tlin) ++by;
  const int bx = by + (tlin - (by * 64 - (by * (by - 1)) / 2));
  const int z = blockIdx.y;
  P += (size_t)z * NROWS * HID;
  if (PASS == 0) M += (size_t)z * NROWS * 64;
  else {
    tauv += (size_t)z * NROWS;
    gcnt += (size_t)z * NROWS;
    gidx += (size_t)z * NROWS * CAP;
  }
  const bool offdiag = (bx != by);
  __shared__ ushort As[TM * BKS];
  __shared__ ushort Bs[TN * BKS];
  __shared__ float Ml[2][TM];
  __shared__ float MlC[4][TN];
  __shared__ float taulA[TM];
  __shared__ float taulB[TN];
  const int tid = threadIdx.x;
  const int wave = tid >> 6, lane = tid & 63;
  const int bm = by * TM;
  const int bn = bx * TN;
  const int wr = (wave >> 1) * 32;
  const int wc = (wave & 1) * 64;

  if (PASS == 1) {
    if (tid < TM) taulA[tid] = tauv[bm + tid];
    else if (tid < TM + TN) taulB[tid - TM] = tauv[bn + (tid - TM)];
  }

  const ushort* pa[2];
  const ushort* pb[2];
  #pragma unroll
  for (int j = 0; j < 2; ++j) {
    const int s = tid + j * 512;
    const int m = s >> 3;
    const int kg = (s & 7) ^ (m & 7);
    pa[j] = P + (size_t)(bm + m) * HID + kg * 8;
    pb[j] = P + (size_t)(bn + m) * HID + kg * 8;
  }

  f32x4 acc[2][4];
  const f32x4 zero = {0.f, 0.f, 0.f, 0.f};
  #pragma unroll
  for (int i = 0; i < 2; ++i)
    #pragma unroll
    for (int j = 0; j < 4; ++j) acc[i][j] = zero;

  for (int k0 = 0; k0 < HID; k0 += BKS) {
    __syncthreads();
    #pragma unroll
    for (int j = 0; j < 2; ++j) {
      load_lds16(pa[j] + k0, &As[(tid + j * 512) * 8]);
      load_lds16(pb[j] + k0, &Bs[(tid + j * 512) * 8]);
    }
    __syncthreads();
    #pragma unroll
    for (int h = 0; h < 2; ++h) {
      const int kgb = h * 4 + (lane >> 4);
      bf16x8 af[2], bf[4];
      #pragma unroll
      for (int f = 0; f < 2; ++f) {
        const int m = wr + f * 16 + (lane & 15);
        const int sa = m * 8 + (kgb ^ (m & 7));
        af[f] = *(const bf16x8*)&As[sa * 8];
      }
      #pragma unroll
      for (int f = 0; f < 4; ++f) {
        const int n = wc + f * 16 + (lane & 15);
        const int sb = n * 8 + (kgb ^ (n & 7));
        bf[f] = *(const bf16x8*)&Bs[sb * 8];
      }
      #pragma unroll
      for (int fr = 0; fr < 2; ++fr)
        #pragma unroll
        for (int fc = 0; fc < 4; ++fc)
          acc[fr][fc] = __builtin_amdgcn_mfma_f32_16x16x32_bf16(af[fr], bf[fc], acc[fr][fc], 0, 0, 0);
    }
  }

  const int cq = lane >> 4, cc = lane & 15;
  if (PASS == 0) {
    #pragma unroll
    for (int fr = 0; fr < 2; ++fr) {
      #pragma unroll
      for (int e = 0; e < 4; ++e) {
        const int lrow = wr + fr * 16 + cq * 4 + e;
        const int grow = bm + lrow;
        float mx = -FLT_MAX;
        #pragma unroll
        for (int fc = 0; fc < 4; ++fc) {
          const int col = bn + wc + fc * 16 + cc;
          mx = fmaxf(mx, (col == grow) ? -FLT_MAX : acc[fr][fc][e]);
        }
        #pragma unroll
        for (int s = 1; s < 16; s <<= 1) mx = fmaxf(mx, __shfl_xor(mx, s));
        if (cc == 0) Ml[wave & 1][lrow] = mx;
      }
    }
    if (offdiag) {
      #pragma unroll
      for (int fc = 0; fc < 4; ++fc) {
        float mx = -FLT_MAX;
        #pragma unroll
        for (int fr = 0; fr < 2; ++fr)
          #pragma unroll
          for (int e = 0; e < 4; ++e) mx = fmaxf(mx, acc[fr][fc][e]);
        mx = fmaxf(mx, __shfl_xor(mx, 16));
        mx = fmaxf(mx, __shfl_xor(mx, 32));
        if (cq == 0) MlC[wave >> 1][wc + fc * 16 + cc] = mx;
      }
    }
    __syncthreads();
    if (tid < TM) M[(size_t)(bm + tid) * 64 + bx] = fmaxf(Ml[0][tid], Ml[1][tid]);
    if (offdiag && tid < TN) {
      const float mx = fmaxf(fmaxf(MlC[0][tid], MlC[1][tid]),
                             fmaxf(MlC[2][tid], MlC[3][tid]));
      M[(size_t)(bn + tid) * 64 + by] = mx;
    }
  } else {
    __syncthreads();
    #pragma unroll
    for (int fr = 0; fr < 2; ++fr) {
      #pragma unroll
      for (int e = 0; e < 4; ++e) {
        const int lrow = wr + fr * 16 + cq * 4 + e;
        const int grow = bm + lrow;
        const float tA = taulA[lrow];
        #pragma unroll
        for (int fc = 0; fc < 4; ++fc) {
          const int lcol = wc + fc * 16 + cc;
          const int gcol = bn + lcol;
          const float v = acc[fr][fc][e];
          if (gcol != grow && v >= tA) {
            const int pos = atomicAdd(&gcnt[grow], 1);
            if (pos < CAP) gidx[(size_t)grow * CAP + pos] = gcol;
          }
          if (offdiag && v >= taulB[lcol]) {
            const int pos = atomicAdd(&gcnt[gcol], 1);
            if (pos < CAP) gidx[(size_t)gcol * CAP + pos] = grow;
          }
        }
      }
    }
  }
}

// ---------------------------------------------------------------------------
// Batched tau: tau[row] = 16th largest of 64 tile-maxes; zeroes gcnt.
// ---------------------------------------------------------------------------
__global__ __launch_bounds__(256) void tau_kernel(const float* __restrict__ M,
    float* __restrict__ tauv, int* __restrict__ gcnt) {
  const int z = blockIdx.y;
  const int wave = threadIdx.x >> 6, lane = threadIdx.x & 63;
  const int row = blockIdx.x * 4 + wave;
  float cur = M[(size_t)z * NROWS * 64 + (size_t)row * 64 + lane];
  float tau = cur;
  #pragma unroll
  for (int sel = 0; sel < 16; ++sel) {
    float bv = cur;
    int bl = lane;
    #pragma unroll
    for (int s = 1; s < 64; s <<= 1) {
      const float ov = __shfl_xor(bv, s);
      const int ol = __shfl_xor(bl, s);
      if (ov > bv || (ov == bv && ol < bl)) { bv = ov; bl = ol; }
    }
    tau = bv;
    if (lane == bl) cur = -FLT_MAX;
  }
  if (lane == 0) {
    tauv[(size_t)z * NROWS + row] = tau;
    gcnt[(size_t)z * NROWS + row] = 0;
  }
}

// ---------------------------------------------------------------------------
// Batched exact refinement: fp32 dots for all candidates, exact top-10.
// R11: SOFTWARE-PIPELINED candidate gather — while the current chunk's
// 64-fmaf chain runs, the next chunk's 16 float4 loads are issued into a
// register buffer (compile-time-indexed, stays in VGPRs). R10 counters
// showed VGPR=52 (no compiler prefetch) and 25% wave duty = pass-serialized
// load-stall; this overlaps the ~500cy gather latency with the 256cy chain.
// Chain order / lane mapping / reduce unchanged -> bit-identical outputs.
// 2 waves per row as R10 (grid NROWS/2 x 3).
// ---------------------------------------------------------------------------
__global__ __launch_bounds__(256) void refine_kernel(const int* __restrict__ gcnt,
    const int* __restrict__ gidx, const float* __restrict__ FN,
    int* __restrict__ nidx, float* __restrict__ nval, float* __restrict__ dinv) {
  const int z = blockIdx.y;
  gcnt += (size_t)z * NROWS;
  gidx += (size_t)z * NROWS * CAP;
  FN += (size_t)z * NROWS * HID;
  nidx += (size_t)z * NROWS * TOPK;
  nval += (size_t)z * NROWS * TOPK;
  dinv += (size_t)z * NROWS;
  const int wave = threadIdx.x >> 6, lane = threadIdx.x & 63;
  const int wr2 = wave >> 1;          // row slot within block (0..1)
  const int w   = wave & 1;           // wave within the row pair
  const int row = blockIdx.x * 2 + wr2;
  const int cnt = min(gcnt[row], CAP);
  __shared__ float fnrow[2][4 * 68];  // 4 segments x 68 floats (padded)
  __shared__ float ev[2][CAP];
  if (w == 0) {
    const float4 v = ((const float4*)(FN + (size_t)row * HID))[lane];
    const int seg = lane >> 4, pos = (lane & 15) * 4;
    *(float4*)&fnrow[wr2][seg * 68 + pos] = v;
  }
  __syncthreads();
  const int c = lane >> 2, q4 = lane & 3;
  const float4* frp = (const float4*)&fnrow[wr2][q4 * 68];
  int b0 = w * 16;
  if (b0 < cnt) {
    float4 buf[16];
    {
      const int ci = b0 + c;
      const int cand = (ci < cnt) ? gidx[(size_t)row * CAP + ci] : 0;
      const float4* fcp = (const float4*)(FN + (size_t)cand * HID + q4 * 64);
      #pragma unroll
      for (int kk = 0; kk < 16; ++kk) buf[kk] = fcp[kk];
    }
    for (; b0 < cnt; b0 += 32) {
      const int nb = b0 + 32;
      float4 nxt[16];
      if (nb < cnt) {
        const int ci2 = nb + c;
        const int cand2 = (ci2 < cnt) ? gidx[(size_t)row * CAP + ci2] : 0;
        const float4* fcp2 = (const float4*)(FN + (size_t)cand2 * HID + q4 * 64);
        #pragma unroll
        for (int kk = 0; kk < 16; ++kk) nxt[kk] = fcp2[kk];
      }
      float s = 0.f;
      #pragma unroll
      for (int kk = 0; kk < 16; ++kk) {
        const float4 a = frp[kk];
        const float4 b = buf[kk];
        s = fmaf(a.x, b.x, s);
        s = fmaf(a.y, b.y, s);
        s = fmaf(a.z, b.z, s);
        s = fmaf(a.w, b.w, s);
      }
      s += __shfl_xor(s, 1);
      s += __shfl_xor(s, 2);
      const int ci = b0 + c;
      if (q4 == 0 && ci < cnt) ev[wr2][ci] = s;
      if (nb < cnt) {
        #pragma unroll
        for (int kk = 0; kk < 16; ++kk) buf[kk] = nxt[kk];
      }
    }
  }
  __syncthreads();
  if (w == 1) return;   // selection handled by wave 0 of each pair
  float outv[TOPK];
  int outi[TOPK];
  float sum = 1.0f;  // diag contributes 1
  #pragma unroll
  for (int sel = 0; sel < TOPK; ++sel) {
    float bv = -FLT_MAX;
    int bp = 0;
    #pragma unroll
    for (int j = 0; j < 4; ++j) {
      const int p = lane + j * 64;
      if (p < cnt) {
        const float v = ev[wr2][p];
        if (v > bv) { bv = v; bp = p; }
      }
    }
    #pragma unroll
    for (int s = 1; s < 64; s <<= 1) {
      const float ov = __shfl_xor(bv, s);
      const int op = __shfl_xor(bp, s);
      if (ov > bv || (ov == bv && op < bp)) { bv = ov; bp = op; }
    }
    outv[sel] = bv;
    outi[sel] = bp;
    sum += fabsf(bv);
    if (lane == 0) ev[wr2][bp] = -FLT_MAX;
  }
  if (lane == 0) {
    const float inv = 1.0f / fmaxf(sum, 1e-12f);
    dinv[row] = inv;
    #pragma unroll
    for (int sel = 0; sel < TOPK; ++sel) {
      nval[row * TOPK + sel] = outv[sel] * inv;
      nidx[row * TOPK + sel] = gidx[(size_t)row * CAP + outi[sel]];
    }
  }
}

// ---------------------------------------------------------------------------
// Batched sparse adj (11 nnz/row) @ T + bias, leaky_relu(0.25).
// EMIT=1: write two-limb bf16 planes (gc2's A side).
// EMIT=0: fused classifier epilogue — the h2 row lives in this block's
//         registers; 5 wave-shuffle reductions produce logits directly
//         (h2 never round-trips HBM).
// ---------------------------------------------------------------------------
template<int EMIT>
__global__ __launch_bounds__(256) void spmm_kernel(const float* __restrict__ T,
    const int* __restrict__ nidx, const float* __restrict__ nval,
    const float* __restrict__ dinv, const float* __restrict__ bias,
    ushort* __restrict__ Hh, ushort* __restrict__ Hl,
    const float* __restrict__ clfW, const float* __restrict__ clfb,
    float* __restrict__ L) {
  const int z = blockIdx.y;
  const size_t zb = (size_t)z * NROWS * HID;
  T += zb;
  nidx += (size_t)z * NROWS * TOPK;
  nval += (size_t)z * NROWS * TOPK;
  dinv += (size_t)z * NROWS;
  const int r = blockIdx.x, c = threadIdx.x;
  float acc = dinv[r] * T[(size_t)r * HID + c];
  #pragma unroll
  for (int n = 0; n < TOPK; ++n) {
    acc += nval[r * TOPK + n] * T[(size_t)nidx[r * TOPK + n] * HID + c];
  }
  acc += bias[z * HID + c];
  const float v = acc >= 0.f ? acc : 0.25f * acc;
  if (EMIT == 1) {
    const size_t o = zb + (size_t)r * HID + c;
    const ushort h = f2bf(v);
    Hh[o] = h;
    Hl[o] = f2bf(v - bf2f(h));
  } else {
    // fused classifier: logits[r][cls] = sum_c v[c] * W[c][cls] + b[cls]
    __shared__ float wsum[4][NCLS];
    const int wave = c >> 6, lane = c & 63;
    const float* wrow = clfW + (size_t)z * HID * NCLS + (size_t)c * NCLS;
    #pragma unroll
    for (int cls = 0; cls < NCLS; ++cls) {
      float p = v * wrow[cls];
      #pragma unroll
      for (int s = 1; s < 64; s <<= 1) p += __shfl_xor(p, s);
      if (lane == 0) wsum[wave][cls] = p;
    }
    __syncthreads();
    if (c < NCLS) {
      const float lg = clfb[z * NCLS + c] + wsum[0][c] + wsum[1][c] + wsum[2][c] + wsum[3][c];
      L[(size_t)z * NROWS * NCLS + (size_t)r * NCLS + c] = lg;
    }
  }
}

__global__ __launch_bounds__(256) void fuse_kernel(const float* __restrict__ L,
    const float* __restrict__ attn, float* __restrict__ fused) {
  const int id = blockIdx.x * 256 + threadIdx.x;
  if (id >= NROWS * NCLS) return;
  const float a0 = attn[0], a1 = attn[1], a2 = attn[2];
  const float m = fmaxf(a0, fmaxf(a1, a2));
  const float e0 = expf(a0 - m), e1 = expf(a1 - m), e2 = expf(a2 - m);
  const float inv = 1.0f / (e0 + e1 + e2);
  const float l0 = L[id];
  const float l1 = L[NROWS * NCLS + id];
  const float l2 = L[2 * NROWS * NCLS + id];
  const float s0 = 1.0f / (1.0f + expf(-l0));
  const float s1 = 1.0f / (1.0f + expf(-l1));
  const float s2 = 1.0f / (1.0f + expf(-l2));
  fused[id] = (e0 * s0 + e1 * s1 + e2 * s2) * inv;
}

__global__ __launch_bounds__(128) void head_kernel(const float* __restrict__ fused,
    const float* __restrict__ W1, const float* __restrict__ b1,
    const float* __restrict__ W2, const float* __restrict__ b2,
    float* __restrict__ out) {
  const int r = blockIdx.x, t = threadIdx.x;
  __shared__ float f[NCLS];
  __shared__ float hh[128];
  if (t < NCLS) f[t] = fused[r * NCLS + t];
  __syncthreads();
  float s = b1[t];
  #pragma unroll
  for (int k = 0; k < NCLS; ++k) s += f[k] * W1[k * 128 + t];
  hh[t] = s >= 0.f ? s : 0.25f * s;
  __syncthreads();
  if (t < NCLS) {
    float o = b2[t];
    for (int k = 0; k < 128; ++k) o += hh[k] * W2[k * NCLS + t];
    out[r * NCLS + t] = o;
  }
}

// ---------------------------------------------------------------------------
extern "C" void kernel_launch(void* const* d_in, const int* in_sizes, int n_in,
                              void* d_out, int out_size, void* d_ws, size_t ws_size,
                              hipStream_t stream) {
  const float* x0 = (const float*)d_in[0];
  const float* x1 = (const float*)d_in[1];
  const float* x2 = (const float*)d_in[2];
  const float* eW0 = (const float*)d_in[3];
  const float* eW1 = (const float*)d_in[4];
  const float* eW2 = (const float*)d_in[5];
  const float* enc_b = (const float*)d_in[6];
  const float* bn_g  = (const float*)d_in[7];
  const float* bn_b  = (const float*)d_in[8];
  const float* gc1W  = (const float*)d_in[9];
  const float* gc1b  = (const float*)d_in[10];
  const float* gc2W  = (const float*)d_in[11];
  const float* gc2b  = (const float*)d_in[12];
  const float* clfW  = (const float*)d_in[13];
  const float* clfb  = (const float*)d_in[14];
  const float* attn  = (const float*)d_in[15];
  const float* f1W   = (const float*)d_in[16];
  const float* f1b   = (const float*)d_in[17];
  const float* f2W   = (const float*)d_in[18];
  const float* f2b   = (const float*)d_in[19];
  float* out = (float*)d_out;

  int Kp[3];
  for (int m = 0; m < 3; ++m) {
    const int D = in_sizes[m] / NROWS;
    int k = 256;
    while (k < D) k <<= 1;
    Kp[m] = k;
  }
  const size_t KpSum = (size_t)Kp[0] + Kp[1] + Kp[2];
  const int D0 = in_sizes[0] / NROWS, D1 = in_sizes[1] / NROWS, D2 = in_sizes[2] / NROWS;

  // ---- Workspace layout with lifetime unions (~151 MB total) ----
  const size_t NH = (size_t)NROWS * HID;   // 2M elems
  float* ws = (float*)d_ws;
  // U1: A (encoder out, dead after bn_rownorm) aliases C (gc gemm temp)
  float* A = ws;                                    // 3*NH
  float* C = A;                                     // alias
  float* nval = A + 3 * NH;
  int*   nidx = (int*)(nval + (size_t)3 * NROWS * TOPK);
  float* dinv = (float*)(nidx + (size_t)3 * NROWS * TOPK);
  float* logits = dinv + 3 * NROWS;
  float* fused = logits + (size_t)3 * NROWS * NCLS;
  float* ps    = fused + (size_t)NROWS * NCLS;
  float* ps2   = ps + 3 * 64 * HID;
  float* scale = ps2 + 3 * 64 * HID;
  float* shift = scale + 3 * HID;
  float* M     = shift + 3 * HID;                   // 3*NROWS*64
  float* tauv  = M + (size_t)3 * NROWS * 64;
  int*   gcnt  = (int*)(tauv + 3 * NROWS);
  int*   gidx  = gcnt + 3 * NROWS;                  // 3*NROWS*CAP
  ushort* WhG = (ushort*)(gidx + (size_t)3 * NROWS * CAP);  // 3*HID*HID
  ushort* WlG = WhG + (size_t)3 * HID * HID;
  ushort* WhE = WlG + (size_t)3 * HID * HID;        // HID*KpSum (compact)
  ushort* WlE = WhE + (size_t)HID * KpSum;
  // U3 (big union): enc A-limb planes (dead after enc gemm) overlay
  //                 FN + Ph + Fh + Fl + Hh + Hl
  char* u3 = (char*)(WlE + (size_t)HID * KpSum);
  float* FN = (float*)u3;                           // 3*NH fp32
  ushort* Ph = (ushort*)(FN + 3 * NH);              // 3*NH each below
  ushort* Fh = Ph + 3 * NH;
  ushort* Fl = Fh + 3 * NH;
  ushort* Hh = Fl + 3 * NH;
  ushort* Hl = Hh + 3 * NH;
  ushort* AhE = (ushort*)u3;                        // NROWS*KpSum (compact)
  ushort* AlE = AhE + (size_t)NROWS * KpSum;

  const size_t aOff0 = 0, aOff1 = (size_t)NROWS * Kp[0],
               aOff2 = (size_t)NROWS * (Kp[0] + Kp[1]);
  const size_t wOff0 = 0, wOff1 = (size_t)HID * Kp[0],
               wOff2 = (size_t)HID * (Kp[0] + Kp[1]);

  const dim3 blk(256);
  // Stage 1: encoder (batched over modalities; packAB 4-wide)
  packAB_kernel<<<dim3(((NROWS + HID) * 1024 / 4) / 256, 3), blk, 0, stream>>>(
      x0, x1, x2, eW0, eW1, eW2, AhE, AlE, WhE, WlE,
      D0, D1, D2, Kp[0], Kp[1], Kp[2], aOff0, aOff1, aOff2, wOff0, wOff1, wOff2);
  limbgemm_kernel<true, 1><<<dim3(128, 3), blk, 0, stream>>>(
      AhE, AlE, WhE, WlE, enc_b, A, Kp[0], Kp[1], Kp[2],
      aOff0, aOff1, aOff2, wOff0, wOff1, wOff2);
  // Stage 2: BN + rownorm + limb emit (AhE/AlE dead; FN..Fl live in U3)
  bn_stats_kernel<<<dim3(64, 3), blk, 0, stream>>>(A, ps, ps2);
  bn_finalize_kernel<<<3, blk, 0, stream>>>(ps, ps2, bn_g, bn_b, scale, shift);
  bn_rownorm_kernel<<<dim3(NROWS, 3), blk, 0, stream>>>(A, scale, shift, FN, Ph, Fh, Fl);
  // Stage 3: symmetric stripe-free knn graph (triangular grid, 2080/z,
  // row-major decode, no dead dispatches; BKS=64 single-buffer)
  simtile_kernel<0><<<dim3(2080, 3), dim3(512), 0, stream>>>(Ph, M, nullptr, nullptr, nullptr);
  tau_kernel<<<dim3(NROWS / 4, 3), blk, 0, stream>>>(M, tauv, gcnt);
  simtile_kernel<1><<<dim3(2080, 3), dim3(512), 0, stream>>>(Ph, nullptr, tauv, gcnt, gidx);
  refine_kernel<<<dim3(NROWS / 2, 3), blk, 0, stream>>>(gcnt, gidx, FN, nidx, nval, dinv);
  // Stage 4: gc1 (A dead -> C reuses U1)
  packW_kernel<<<dim3(256, 3), blk, 0, stream>>>(gc1W, WhG, WlG);
  limbgemm_kernel<false, 0><<<dim3(128, 3), blk, 0, stream>>>(
      Fh, Fl, WhG, WlG, nullptr, C, HID, HID, HID,
      0, NH, 2 * NH, 0, (size_t)HID * HID, (size_t)2 * HID * HID);
  spmm_kernel<1><<<dim3(NROWS, 3), blk, 0, stream>>>(C, nidx, nval, dinv, gc1b,
                                                     Hh, Hl, nullptr, nullptr, nullptr);
  // Stage 5: gc2 + fused classifier (h2 never hits HBM)
  packW_kernel<<<dim3(256, 3), blk, 0, stream>>>(gc2W, WhG, WlG);
  limbgemm_kernel<false, 0><<<dim3(128, 3), blk, 0, stream>>>(
      Hh, Hl, WhG, WlG, nullptr, C, HID, HID, HID,
      0, NH, 2 * NH, 0, (size_t)HID * HID, (size_t)2 * HID * HID);
  spmm_kernel<0><<<dim3(NROWS, 3), blk, 0, stream>>>(C, nidx, nval, dinv, gc2b,
                                                     nullptr, nullptr, clfW, clfb, logits);
  // Stage 6: fusion head
  fuse_kernel<<<(NROWS * NCLS + 255) / 256, blk, 0, stream>>>(logits, attn, fused);
  head_kernel<<<NROWS, dim3(128), 0, stream>>>(fused, f1W, f1b, f2W, f2b, out);
}

// Round 12
// 742.459 us; speedup vs baseline: 1.0469x; 1.0469x over previous
//
#include <hip/hip_runtime.h>
#include <cfloat>
#include <cstdint>
#include <cstddef>

#define NROWS 8192
#define HID 256
#define NCLS 5
#define TOPK 10
#define CAP 256     // per-row candidate capacity (typ. ~20-60 used)
#define TM 128
#define TN 128
#define BK 32
#define BKS 64      // sim K-step

typedef __bf16 bf16x8 __attribute__((ext_vector_type(8)));
typedef float f32x4 __attribute__((ext_vector_type(4)));
typedef unsigned short us4 __attribute__((ext_vector_type(4)));

__device__ inline ushort f2bf(float x) {
  unsigned u = __float_as_uint(x);
  unsigned r = (u + 0x7fffu + ((u >> 16) & 1u)) >> 16;  // RNE
  return (ushort)r;
}
__device__ inline float bf2f(ushort b) { return __uint_as_float(((unsigned)b) << 16); }

// async global->LDS 16B/lane; LDS dest is wave-uniform base + lane*16
__device__ __forceinline__ void load_lds16(const void* g, void* l) {
  __builtin_amdgcn_global_load_lds(
      (const __attribute__((address_space(1))) void*)g,
      (__attribute__((address_space(3))) void*)l, 16, 0, 0);
}

// ---------------------------------------------------------------------------
// Batched encoder pack, 4-WIDE (z = modality): X -> hi/lo limb planes
// (COMPACT per-z row stride Kp[z], zero-padded past D), W -> transposed
// [HID x Kp[z]] planes. float4 loads (alignment-guarded) + ushort4 stores;
// per-element RNE math unchanged -> bit-identical values. (R7-verified:
// rest-of-pipeline -44 us vs scalar.)
// ---------------------------------------------------------------------------
__global__ __launch_bounds__(256) void packAB_kernel(const float* __restrict__ X0,
    const float* __restrict__ X1, const float* __restrict__ X2,
    const float* __restrict__ W0, const float* __restrict__ W1,
    const float* __restrict__ W2, ushort* __restrict__ Ah, ushort* __restrict__ Al,
    ushort* __restrict__ Bh, ushort* __restrict__ Bl,
    int D0, int D1, int D2, int Kp0, int Kp1, int Kp2,
    size_t aOff0, size_t aOff1, size_t aOff2,
    size_t wOff0, size_t wOff1, size_t wOff2) {
  const int z = blockIdx.y;
  const float* X = (z == 0) ? X0 : (z == 1) ? X1 : X2;
  const float* W = (z == 0) ? W0 : (z == 1) ? W1 : W2;
  const int D = (z == 0) ? D0 : (z == 1) ? D1 : D2;
  const int Kp = (z == 0) ? Kp0 : (z == 1) ? Kp1 : Kp2;
  const size_t aOff = (z == 0) ? aOff0 : (z == 1) ? aOff1 : aOff2;
  const size_t wOff = (z == 0) ? wOff0 : (z == 1) ? wOff1 : wOff2;
  const int ksh2 = (31 - __clz(Kp)) - 2;     // log2(Kp/4)
  const int id4 = blockIdx.x * 256 + threadIdx.x;
  const int aq = NROWS << ksh2;
  const int wq = HID << ksh2;
  if (id4 >= aq + wq) return;
  float x[4];
  ushort h[4], l[4];
  if (id4 < aq) {
    const int kq = id4 & ((Kp >> 2) - 1);
    const int r = id4 >> ksh2;
    const int k = kq << 2;
    const float* src = X + (size_t)r * D + k;
    if (k + 3 < D && ((((size_t)r * D + k) & 3) == 0)) {
      const float4 v = *(const float4*)src;
      x[0] = v.x; x[1] = v.y; x[2] = v.z; x[3] = v.w;
    } else {
      #pragma unroll
      for (int j = 0; j < 4; ++j) x[j] = (k + j < D) ? src[j] : 0.f;
    }
    #pragma unroll
    for (int j = 0; j < 4; ++j) { h[j] = f2bf(x[j]); l[j] = f2bf(x[j] - bf2f(h[j])); }
    const size_t o = aOff + (((size_t)r) << (ksh2 + 2)) + k;
    *(us4*)&Ah[o] = (us4){h[0], h[1], h[2], h[3]};
    *(us4*)&Al[o] = (us4){l[0], l[1], l[2], l[3]};
  } else {
    const int id2 = id4 - aq;
    const int kq = id2 & ((Kp >> 2) - 1);
    const int n = id2 >> ksh2;
    const int k = kq << 2;
    #pragma unroll
    for (int j = 0; j < 4; ++j) {
      const float xv = (k + j < D) ? W[(size_t)(k + j) * HID + n] : 0.f;
      h[j] = f2bf(xv); l[j] = f2bf(xv - bf2f(h[j]));
    }
    const size_t o = wOff + (((size_t)n) << (ksh2 + 2)) + k;
    *(us4*)&Bh[o] = (us4){h[0], h[1], h[2], h[3]};
    *(us4*)&Bl[o] = (us4){l[0], l[1], l[2], l[3]};
  }
}

// ---------------------------------------------------------------------------
// Batched GCN weight pack: W[z] [HID x HID] -> transposed limb planes.
// ---------------------------------------------------------------------------
__global__ __launch_bounds__(256) void packW_kernel(const float* __restrict__ W,
    ushort* __restrict__ Bh, ushort* __restrict__ Bl) {
  const int z = blockIdx.y;
  const int id = blockIdx.x * 256 + threadIdx.x;  // 65536 per z
  const int k = id >> 8, n = id & 255;
  const size_t wz = (size_t)z * HID * HID;
  const float x = W[wz + (size_t)k * HID + n];
  const ushort h = f2bf(x);
  Bh[wz + (size_t)n * HID + k] = h;
  Bl[wz + (size_t)n * HID + k] = f2bf(x - bf2f(h));
}

// ---------------------------------------------------------------------------
// Batched 3-segment two-limb bf16 MFMA GEMM, 128x128 tile. 4 waves (2x2),
// wave = 64x64 = acc[4][4]. Staging/fragment swizzle = proven R4 mapping.
// 2-PHASE double-buffered staging: step t issues global_load_lds for t+1
// BEFORE computing t; ONE __syncthreads per step (drain overlaps compute).
// Per-k accumulation order (hh,hl,lh) unchanged -> bit-identical results.
// ---------------------------------------------------------------------------
#define STAGE_LIMB(B, K0)                              \
    load_lds16(Ah + a0 + (K0), &AsH[B][p0 * 8]);       \
    load_lds16(Ah + a1 + (K0), &AsH[B][p1 * 8]);       \
    load_lds16(Al + a0 + (K0), &AsL[B][p0 * 8]);       \
    load_lds16(Al + a1 + (K0), &AsL[B][p1 * 8]);       \
    load_lds16(Bh + b0 + (K0), &BsH[B][p0 * 8]);       \
    load_lds16(Bh + b1 + (K0), &BsH[B][p1 * 8]);       \
    load_lds16(Bl + b0 + (K0), &BsL[B][p0 * 8]);       \
    load_lds16(Bl + b1 + (K0), &BsL[B][p1 * 8]);

template<bool BIAS, int ACT>
__global__ __launch_bounds__(256) void limbgemm_kernel(const ushort* __restrict__ Ah,
    const ushort* __restrict__ Al, const ushort* __restrict__ Bh,
    const ushort* __restrict__ Bl, const float* __restrict__ bias,
    float* __restrict__ C, int Kp0, int Kp1, int Kp2,
    size_t aOff0, size_t aOff1, size_t aOff2,
    size_t bOff0, size_t bOff1, size_t bOff2) {
  __shared__ ushort AsH[2][TM * BK], AsL[2][TM * BK], BsH[2][TM * BK], BsL[2][TM * BK];
  const int z = blockIdx.y;
  const int Kp = (z == 0) ? Kp0 : (z == 1) ? Kp1 : Kp2;
  const size_t aO = (z == 0) ? aOff0 : (z == 1) ? aOff1 : aOff2;
  const size_t bO = (z == 0) ? bOff0 : (z == 1) ? bOff1 : bOff2;
  Ah += aO; Al += aO; Bh += bO; Bl += bO;
  C += (size_t)z * NROWS * HID;
  const int tid = threadIdx.x;
  const int wave = tid >> 6, lane = tid & 63;
  // XCD swizzle: 128 blocks = 64 row-blocks x 2 col-blocks
  const int bid = blockIdx.x;
  const int xcd = bid & 7, slot = bid >> 3;      // slot 0..15
  const int bxi = slot & 1;
  const int byi = xcd * 8 + (slot >> 1);
  const int bm = byi * TM, bn = bxi * 128;
  const int wr = (wave >> 1) * 64, wc = (wave & 1) * 64;

  f32x4 acc[4][4];
  const f32x4 zero = {0.f, 0.f, 0.f, 0.f};
  #pragma unroll
  for (int i = 0; i < 4; ++i)
    #pragma unroll
    for (int j = 0; j < 4; ++j) acc[i][j] = zero;

  // staging slots (proven R4 mapping): p in {tid, tid+256}, r=p>>2,
  // kl = (p&3) ^ ((r&3) ^ ((r>>2)&1))
  const int p0 = tid, p1 = tid + 256;
  const int r0 = p0 >> 2, kl0 = (p0 & 3) ^ ((r0 & 3) ^ ((r0 >> 2) & 1));
  const int r1 = p1 >> 2, kl1 = (p1 & 3) ^ ((r1 & 3) ^ ((r1 >> 2) & 1));
  const size_t a0 = (size_t)(bm + r0) * Kp + kl0 * 8;
  const size_t a1 = (size_t)(bm + r1) * Kp + kl1 * 8;
  const size_t b0 = (size_t)(bn + r0) * Kp + kl0 * 8;
  const size_t b1 = (size_t)(bn + r1) * Kp + kl1 * 8;

  // prologue: stage k0=0 into buffer 0
  STAGE_LIMB(0, 0)
  __syncthreads();
  int cur = 0;
  for (int k0 = 0; k0 < Kp; k0 += BK) {
    if (k0 + BK < Kp) {
      STAGE_LIMB(cur ^ 1, k0 + BK)
    }
    bf16x8 ah[4], al[4], bh[4], bl[4];
    const int kg = lane >> 4;
    #pragma unroll
    for (int f = 0; f < 4; ++f) {
      const int m = wr + f * 16 + (lane & 15);
      const int sa = m * 4 + (kg ^ (m & 3) ^ ((m >> 2) & 1));
      ah[f] = *(const bf16x8*)&AsH[cur][sa * 8];
      al[f] = *(const bf16x8*)&AsL[cur][sa * 8];
      const int n = wc + f * 16 + (lane & 15);
      const int sb = n * 4 + (kg ^ (n & 3) ^ ((n >> 2) & 1));
      bh[f] = *(const bf16x8*)&BsH[cur][sb * 8];
      bl[f] = *(const bf16x8*)&BsL[cur][sb * 8];
    }
    #pragma unroll
    for (int fr = 0; fr < 4; ++fr)
      #pragma unroll
      for (int fc = 0; fc < 4; ++fc) {
        acc[fr][fc] = __builtin_amdgcn_mfma_f32_16x16x32_bf16(ah[fr], bh[fc], acc[fr][fc], 0, 0, 0);
        acc[fr][fc] = __builtin_amdgcn_mfma_f32_16x16x32_bf16(ah[fr], bl[fc], acc[fr][fc], 0, 0, 0);
        acc[fr][fc] = __builtin_amdgcn_mfma_f32_16x16x32_bf16(al[fr], bh[fc], acc[fr][fc], 0, 0, 0);
      }
    __syncthreads();
    cur ^= 1;
  }
  const int cq = lane >> 4, cc = lane & 15;
  #pragma unroll
  for (int fr = 0; fr < 4; ++fr) {
    #pragma unroll
    for (int fc = 0; fc < 4; ++fc) {
      const int rb = bm + wr + fr * 16 + cq * 4;
      const int col = bn + wc + fc * 16 + cc;
      const float bb = BIAS ? bias[z * HID + col] : 0.f;
      float* cp = C + (size_t)rb * HID + col;
      #pragma unroll
      for (int e = 0; e < 4; ++e) {
        float v = acc[fr][fc][e] + bb;
        if (ACT == 1) v = fmaxf(v, 0.f);
        cp[(size_t)e * HID] = v;
      }
    }
  }
}

// ---------------------------------------------------------------------------
// Batched coalesced BatchNorm, 3 stages.
// ---------------------------------------------------------------------------
__global__ __launch_bounds__(256) void bn_stats_kernel(const float* __restrict__ F,
    float* __restrict__ ps, float* __restrict__ ps2) {
  const int z = blockIdx.y;
  const int b = blockIdx.x, t = threadIdx.x;
  float s = 0.f, s2 = 0.f;
  const float* p = F + (size_t)z * NROWS * HID + (size_t)b * 128 * HID + t;
  for (int r = 0; r < 128; ++r) {
    const float v = p[(size_t)r * HID];
    s += v; s2 += v * v;
  }
  ps[(size_t)z * 64 * HID + b * HID + t] = s;
  ps2[(size_t)z * 64 * HID + b * HID + t] = s2;
}

__global__ __launch_bounds__(256) void bn_finalize_kernel(const float* __restrict__ ps,
    const float* __restrict__ ps2, const float* __restrict__ g,
    const float* __restrict__ b, float* __restrict__ scale, float* __restrict__ shift) {
  const int z = blockIdx.x;
  const int t = threadIdx.x;
  float s = 0.f, s2 = 0.f;
  for (int i = 0; i < 64; ++i) {
    s += ps[(size_t)z * 64 * HID + i * HID + t];
    s2 += ps2[(size_t)z * 64 * HID + i * HID + t];
  }
  const float mu = s / (float)NROWS;
  const float var = s2 / (float)NROWS - mu * mu;
  const float rstd = rsqrtf(var + 1e-5f);
  const float sc = rstd * g[z * HID + t];
  scale[z * HID + t] = sc;
  shift[z * HID + t] = b[z * HID + t] - mu * sc;
}

// ---------------------------------------------------------------------------
// Batched fused bn-apply + L2 rownorm. Emits FN, Ph (hi-limb fn), Fh/Fl.
// ---------------------------------------------------------------------------
__global__ __launch_bounds__(256) void bn_rownorm_kernel(const float* __restrict__ F,
    const float* __restrict__ scale, const float* __restrict__ shift,
    float* __restrict__ FN, ushort* __restrict__ Ph,
    ushort* __restrict__ Fh, ushort* __restrict__ Fl) {
  const int z = blockIdx.y;
  const int r = blockIdx.x, t = threadIdx.x;
  const size_t zb = (size_t)z * NROWS * HID;
  const float f = F[zb + (size_t)r * HID + t] * scale[z * HID + t] + shift[z * HID + t];
  __shared__ float sh[256];
  sh[t] = f * f;
  __syncthreads();
  for (int st = 128; st > 0; st >>= 1) {
    if (t < st) sh[t] += sh[t + st];
    __syncthreads();
  }
  const float inv = 1.0f / fmaxf(sqrtf(sh[0]), 1e-12f);
  const float fn = f * inv;
  const size_t o = zb + (size_t)r * HID + t;
  FN[o] = fn;
  Ph[o] = f2bf(fn);
  const ushort h = f2bf(f);
  Fh[o] = h;
  Fl[o] = f2bf(f - bf2f(h));
}

// ---------------------------------------------------------------------------
// Batched SYMMETRIC stripe-free sim: TRIANGULAR grid (2080/z, row-major
// decode, no dead dispatches). R6-VERIFIED config: BKS=64 single-buffer,
// 33 KB LDS, m*8+(kgb^(m&7)) swizzle — measured 118 us, 0 bank conflicts.
// (BK=32-style mapping REGRESSES: 9.58M conflicts, +25 us — R7.)
// PASS 0: per-row/per-col tile maxes -> M. PASS 1: tau-compaction both dirs.
// ---------------------------------------------------------------------------
template<int PASS>
__global__ __launch_bounds__(512) void simtile_kernel(const ushort* __restrict__ P,
    float* __restrict__ M, const float* __restrict__ tauv,
    int* __restrict__ gcnt, int* __restrict__ gidx) {
  // row-major upper-triangle decode: tlin -> (by, bx) with by <= bx < 64.
  const int tlin = blockIdx.x;
  int by = (int)(64.5f - sqrtf(4160.25f - 2.0f * (float)tlin));
  if (by < 0) by = 0;
  if (by > 63) by = 63;
  while (by > 0 && (by * 64 - (by * (by - 1)) / 2) > tlin) --by;
  while (by < 63 && ((by + 1) * 64 - ((by + 1) * by) / 2) <= tlin) ++by;
  const int bx = by + (tlin - (by * 64 - (by * (by - 1)) / 2));
  const int z = blockIdx.y;
  P += (size_t)z * NROWS * HID;
  if (PASS == 0) M += (size_t)z * NROWS * 64;
  else {
    tauv += (size_t)z * NROWS;
    gcnt += (size_t)z * NROWS;
    gidx += (size_t)z * NROWS * CAP;
  }
  const bool offdiag = (bx != by);
  __shared__ ushort As[TM * BKS];
  __shared__ ushort Bs[TN * BKS];
  __shared__ float Ml[2][TM];
  __shared__ float MlC[4][TN];
  __shared__ float taulA[TM];
  __shared__ float taulB[TN];
  const int tid = threadIdx.x;
  const int wave = tid >> 6, lane = tid & 63;
  const int bm = by * TM;
  const int bn = bx * TN;
  const int wr = (wave >> 1) * 32;
  const int wc = (wave & 1) * 64;

  if (PASS == 1) {
    if (tid < TM) taulA[tid] = tauv[bm + tid];
    else if (tid < TM + TN) taulB[tid - TM] = tauv[bn + (tid - TM)];
  }

  const ushort* pa[2];
  const ushort* pb[2];
  #pragma unroll
  for (int j = 0; j < 2; ++j) {
    const int s = tid + j * 512;
    const int m = s >> 3;
    const int kg = (s & 7) ^ (m & 7);
    pa[j] = P + (size_t)(bm + m) * HID + kg * 8;
    pb[j] = P + (size_t)(bn + m) * HID + kg * 8;
  }

  f32x4 acc[2][4];
  const f32x4 zero = {0.f, 0.f, 0.f, 0.f};
  #pragma unroll
  for (int i = 0; i < 2; ++i)
    #pragma unroll
    for (int j = 0; j < 4; ++j) acc[i][j] = zero;

  for (int k0 = 0; k0 < HID; k0 += BKS) {
    __syncthreads();
    #pragma unroll
    for (int j = 0; j < 2; ++j) {
      load_lds16(pa[j] + k0, &As[(tid + j * 512) * 8]);
      load_lds16(pb[j] + k0, &Bs[(tid + j * 512) * 8]);
    }
    __syncthreads();
    #pragma unroll
    for (int h = 0; h < 2; ++h) {
      const int kgb = h * 4 + (lane >> 4);
      bf16x8 af[2], bf[4];
      #pragma unroll
      for (int f = 0; f < 2; ++f) {
        const int m = wr + f * 16 + (lane & 15);
        const int sa = m * 8 + (kgb ^ (m & 7));
        af[f] = *(const bf16x8*)&As[sa * 8];
      }
      #pragma unroll
      for (int f = 0; f < 4; ++f) {
        const int n = wc + f * 16 + (lane & 15);
        const int sb = n * 8 + (kgb ^ (n & 7));
        bf[f] = *(const bf16x8*)&Bs[sb * 8];
      }
      #pragma unroll
      for (int fr = 0; fr < 2; ++fr)
        #pragma unroll
        for (int fc = 0; fc < 4; ++fc)
          acc[fr][fc] = __builtin_amdgcn_mfma_f32_16x16x32_bf16(af[fr], bf[fc], acc[fr][fc], 0, 0, 0);
    }
  }

  const int cq = lane >> 4, cc = lane & 15;
  if (PASS == 0) {
    #pragma unroll
    for (int fr = 0; fr < 2; ++fr) {
      #pragma unroll
      for (int e = 0; e < 4; ++e) {
        const int lrow = wr + fr * 16 + cq * 4 + e;
        const int grow = bm + lrow;
        float mx = -FLT_MAX;
        #pragma unroll
        for (int fc = 0; fc < 4; ++fc) {
          const int col = bn + wc + fc * 16 + cc;
          mx = fmaxf(mx, (col == grow) ? -FLT_MAX : acc[fr][fc][e]);
        }
        #pragma unroll
        for (int s = 1; s < 16; s <<= 1) mx = fmaxf(mx, __shfl_xor(mx, s));
        if (cc == 0) Ml[wave & 1][lrow] = mx;
      }
    }
    if (offdiag) {
      #pragma unroll
      for (int fc = 0; fc < 4; ++fc) {
        float mx = -FLT_MAX;
        #pragma unroll
        for (int fr = 0; fr < 2; ++fr)
          #pragma unroll
          for (int e = 0; e < 4; ++e) mx = fmaxf(mx, acc[fr][fc][e]);
        mx = fmaxf(mx, __shfl_xor(mx, 16));
        mx = fmaxf(mx, __shfl_xor(mx, 32));
        if (cq == 0) MlC[wave >> 1][wc + fc * 16 + cc] = mx;
      }
    }
    __syncthreads();
    if (tid < TM) M[(size_t)(bm + tid) * 64 + bx] = fmaxf(Ml[0][tid], Ml[1][tid]);
    if (offdiag && tid < TN) {
      const float mx = fmaxf(fmaxf(MlC[0][tid], MlC[1][tid]),
                             fmaxf(MlC[2][tid], MlC[3][tid]));
      M[(size_t)(bn + tid) * 64 + by] = mx;
    }
  } else {
    __syncthreads();
    #pragma unroll
    for (int fr = 0; fr < 2; ++fr) {
      #pragma unroll
      for (int e = 0; e < 4; ++e) {
        const int lrow = wr + fr * 16 + cq * 4 + e;
        const int grow = bm + lrow;
        const float tA = taulA[lrow];
        #pragma unroll
        for (int fc = 0; fc < 4; ++fc) {
          const int lcol = wc + fc * 16 + cc;
          const int gcol = bn + lcol;
          const float v = acc[fr][fc][e];
          if (gcol != grow && v >= tA) {
            const int pos = atomicAdd(&gcnt[grow], 1);
            if (pos < CAP) gidx[(size_t)grow * CAP + pos] = gcol;
          }
          if (offdiag && v >= taulB[lcol]) {
            const int pos = atomicAdd(&gcnt[gcol], 1);
            if (pos < CAP) gidx[(size_t)gcol * CAP + pos] = grow;
          }
        }
      }
    }
  }
}

// ---------------------------------------------------------------------------
// Batched tau: tau[row] = 16th largest of 64 tile-maxes; zeroes gcnt.
// ---------------------------------------------------------------------------
__global__ __launch_bounds__(256) void tau_kernel(const float* __restrict__ M,
    float* __restrict__ tauv, int* __restrict__ gcnt) {
  const int z = blockIdx.y;
  const int wave = threadIdx.x >> 6, lane = threadIdx.x & 63;
  const int row = blockIdx.x * 4 + wave;
  float cur = M[(size_t)z * NROWS * 64 + (size_t)row * 64 + lane];
  float tau = cur;
  #pragma unroll
  for (int sel = 0; sel < 16; ++sel) {
    float bv = cur;
    int bl = lane;
    #pragma unroll
    for (int s = 1; s < 64; s <<= 1) {
      const float ov = __shfl_xor(bv, s);
      const int ol = __shfl_xor(bl, s);
      if (ov > bv || (ov == bv && ol < bl)) { bv = ov; bl = ol; }
    }
    tau = bv;
    if (lane == bl) cur = -FLT_MAX;
  }
  if (lane == 0) {
    tauv[(size_t)z * NROWS + row] = tau;
    gcnt[(size_t)z * NROWS + row] = 0;
  }
}

// ---------------------------------------------------------------------------
// Batched exact refinement: fp32 dots for all candidates, exact top-10.
// R12: LOAD-BALANCED chunk scheduling — 4 rows/block, but the 4 waves share
// the block's FLATTENED chunk list (prefix-sum over ceil(cnt_i/16); wave w
// takes chunks w, w+4, ...). A cnt=256 straggler row costs ~ceil(total/4)
// passes instead of 16 serial passes on one wave. VGPR unchanged (~52; the
// R11 register-pipeline pushed 108 and halved occupancy — reverted).
// Per-chunk dot = identical 64-fmaf chain + shfl reduce -> ev bit-identical;
// selection (wave i -> row i) is the R9 code verbatim -> outputs
// bit-identical.
// ---------------------------------------------------------------------------
__global__ __launch_bounds__(256) void refine_kernel(const int* __restrict__ gcnt,
    const int* __restrict__ gidx, const float* __restrict__ FN,
    int* __restrict__ nidx, float* __restrict__ nval, float* __restrict__ dinv) {
  const int z = blockIdx.y;
  gcnt += (size_t)z * NROWS;
  gidx += (size_t)z * NROWS * CAP;
  FN += (size_t)z * NROWS * HID;
  nidx += (size_t)z * NROWS * TOPK;
  nval += (size_t)z * NROWS * TOPK;
  dinv += (size_t)z * NROWS;
  const int wave = threadIdx.x >> 6, lane = threadIdx.x & 63;
  const int rbase = blockIdx.x * 4;
  int cnt4[4], pre[5];
  pre[0] = 0;
  #pragma unroll
  for (int i = 0; i < 4; ++i) {
    cnt4[i] = min(gcnt[rbase + i], CAP);
    pre[i + 1] = pre[i] + ((cnt4[i] + 15) >> 4);
  }
  const int total = pre[4];
  __shared__ float fnrow[4][4 * 68];   // padded: 4 segments x 68 floats
  __shared__ float ev[4][CAP];
  {
    const float4 v = ((const float4*)(FN + (size_t)(rbase + wave) * HID))[lane];
    const int seg = lane >> 4, pos = (lane & 15) * 4;
    *(float4*)&fnrow[wave][seg * 68 + pos] = v;
  }
  __syncthreads();
  const int c = lane >> 2, q4 = lane & 3;
  for (int j = wave; j < total; j += 4) {
    int i = 0;
    while (j >= pre[i + 1]) ++i;       // wave-uniform scan, i in 0..3
    const int row = rbase + i;
    const int cnt = cnt4[i];
    const int b0 = (j - pre[i]) * 16;
    const int ci = b0 + c;
    const int cand = (ci < cnt) ? gidx[(size_t)row * CAP + ci] : 0;
    const float4* frp = (const float4*)&fnrow[i][q4 * 68];
    const float4* fcp = (const float4*)(FN + (size_t)cand * HID + q4 * 64);
    float s = 0.f;
    #pragma unroll
    for (int kk = 0; kk < 16; ++kk) {
      const float4 a = frp[kk];
      const float4 b = fcp[kk];
      s = fmaf(a.x, b.x, s);
      s = fmaf(a.y, b.y, s);
      s = fmaf(a.z, b.z, s);
      s = fmaf(a.w, b.w, s);
    }
    s += __shfl_xor(s, 1);
    s += __shfl_xor(s, 2);
    if (q4 == 0 && ci < cnt) ev[i][ci] = s;
  }
  __syncthreads();
  // selection: wave i handles row i (R9-identical)
  const int row = rbase + wave;
  const int cnt = cnt4[wave];
  float outv[TOPK];
  int outi[TOPK];
  float sum = 1.0f;  // diag contributes 1
  #pragma unroll
  for (int sel = 0; sel < TOPK; ++sel) {
    float bv = -FLT_MAX;
    int bp = 0;
    #pragma unroll
    for (int j = 0; j < 4; ++j) {
      const int p = lane + j * 64;
      if (p < cnt) {
        const float v = ev[wave][p];
        if (v > bv) { bv = v; bp = p; }
      }
    }
    #pragma unroll
    for (int s = 1; s < 64; s <<= 1) {
      const float ov = __shfl_xor(bv, s);
      const int op = __shfl_xor(bp, s);
      if (ov > bv || (ov == bv && op < bp)) { bv = ov; bp = op; }
    }
    outv[sel] = bv;
    outi[sel] = bp;
    sum += fabsf(bv);
    if (lane == 0) ev[wave][bp] = -FLT_MAX;
  }
  if (lane == 0) {
    const float inv = 1.0f / fmaxf(sum, 1e-12f);
    dinv[row] = inv;
    #pragma unroll
    for (int sel = 0; sel < TOPK; ++sel) {
      nval[row * TOPK + sel] = outv[sel] * inv;
      nidx[row * TOPK + sel] = gidx[(size_t)row * CAP + outi[sel]];
    }
  }
}

// ---------------------------------------------------------------------------
// Batched sparse adj (11 nnz/row) @ T + bias, leaky_relu(0.25).
// EMIT=1: write two-limb bf16 planes (gc2's A side).
// EMIT=0: fused classifier epilogue — the h2 row lives in this block's
//         registers; 5 wave-shuffle reductions produce logits directly
//         (h2 never round-trips HBM).
// ---------------------------------------------------------------------------
template<int EMIT>
__global__ __launch_bounds__(256) void spmm_kernel(const float* __restrict__ T,
    const int* __restrict__ nidx, const float* __restrict__ nval,
    const float* __restrict__ dinv, const float* __restrict__ bias,
    ushort* __restrict__ Hh, ushort* __restrict__ Hl,
    const float* __restrict__ clfW, const float* __restrict__ clfb,
    float* __restrict__ L) {
  const int z = blockIdx.y;
  const size_t zb = (size_t)z * NROWS * HID;
  T += zb;
  nidx += (size_t)z * NROWS * TOPK;
  nval += (size_t)z * NROWS * TOPK;
  dinv += (size_t)z * NROWS;
  const int r = blockIdx.x, c = threadIdx.x;
  float acc = dinv[r] * T[(size_t)r * HID + c];
  #pragma unroll
  for (int n = 0; n < TOPK; ++n) {
    acc += nval[r * TOPK + n] * T[(size_t)nidx[r * TOPK + n] * HID + c];
  }
  acc += bias[z * HID + c];
  const float v = acc >= 0.f ? acc : 0.25f * acc;
  if (EMIT == 1) {
    const size_t o = zb + (size_t)r * HID + c;
    const ushort h = f2bf(v);
    Hh[o] = h;
    Hl[o] = f2bf(v - bf2f(h));
  } else {
    // fused classifier: logits[r][cls] = sum_c v[c] * W[c][cls] + b[cls]
    __shared__ float wsum[4][NCLS];
    const int wave = c >> 6, lane = c & 63;
    const float* wrow = clfW + (size_t)z * HID * NCLS + (size_t)c * NCLS;
    #pragma unroll
    for (int cls = 0; cls < NCLS; ++cls) {
      float p = v * wrow[cls];
      #pragma unroll
      for (int s = 1; s < 64; s <<= 1) p += __shfl_xor(p, s);
      if (lane == 0) wsum[wave][cls] = p;
    }
    __syncthreads();
    if (c < NCLS) {
      const float lg = clfb[z * NCLS + c] + wsum[0][c] + wsum[1][c] + wsum[2][c] + wsum[3][c];
      L[(size_t)z * NROWS * NCLS + (size_t)r * NCLS + c] = lg;
    }
  }
}

__global__ __launch_bounds__(256) void fuse_kernel(const float* __restrict__ L,
    const float* __restrict__ attn, float* __restrict__ fused) {
  const int id = blockIdx.x * 256 + threadIdx.x;
  if (id >= NROWS * NCLS) return;
  const float a0 = attn[0], a1 = attn[1], a2 = attn[2];
  const float m = fmaxf(a0, fmaxf(a1, a2));
  const float e0 = expf(a0 - m), e1 = expf(a1 - m), e2 = expf(a2 - m);
  const float inv = 1.0f / (e0 + e1 + e2);
  const float l0 = L[id];
  const float l1 = L[NROWS * NCLS + id];
  const float l2 = L[2 * NROWS * NCLS + id];
  const float s0 = 1.0f / (1.0f + expf(-l0));
  const float s1 = 1.0f / (1.0f + expf(-l1));
  const float s2 = 1.0f / (1.0f + expf(-l2));
  fused[id] = (e0 * s0 + e1 * s1 + e2 * s2) * inv;
}

__global__ __launch_bounds__(128) void head_kernel(const float* __restrict__ fused,
    const float* __restrict__ W1, const float* __restrict__ b1,
    const float* __restrict__ W2, const float* __restrict__ b2,
    float* __restrict__ out) {
  const int r = blockIdx.x, t = threadIdx.x;
  __shared__ float f[NCLS];
  __shared__ float hh[128];
  if (t < NCLS) f[t] = fused[r * NCLS + t];
  __syncthreads();
  float s = b1[t];
  #pragma unroll
  for (int k = 0; k < NCLS; ++k) s += f[k] * W1[k * 128 + t];
  hh[t] = s >= 0.f ? s : 0.25f * s;
  __syncthreads();
  if (t < NCLS) {
    float o = b2[t];
    for (int k = 0; k < 128; ++k) o += hh[k] * W2[k * NCLS + t];
    out[r * NCLS + t] = o;
  }
}

// ---------------------------------------------------------------------------
extern "C" void kernel_launch(void* const* d_in, const int* in_sizes, int n_in,
                              void* d_out, int out_size, void* d_ws, size_t ws_size,
                              hipStream_t stream) {
  const float* x0 = (const float*)d_in[0];
  const float* x1 = (const float*)d_in[1];
  const float* x2 = (const float*)d_in[2];
  const float* eW0 = (const float*)d_in[3];
  const float* eW1 = (const float*)d_in[4];
  const float* eW2 = (const float*)d_in[5];
  const float* enc_b = (const float*)d_in[6];
  const float* bn_g  = (const float*)d_in[7];
  const float* bn_b  = (const float*)d_in[8];
  const float* gc1W  = (const float*)d_in[9];
  const float* gc1b  = (const float*)d_in[10];
  const float* gc2W  = (const float*)d_in[11];
  const float* gc2b  = (const float*)d_in[12];
  const float* clfW  = (const float*)d_in[13];
  const float* clfb  = (const float*)d_in[14];
  const float* attn  = (const float*)d_in[15];
  const float* f1W   = (const float*)d_in[16];
  const float* f1b   = (const float*)d_in[17];
  const float* f2W   = (const float*)d_in[18];
  const float* f2b   = (const float*)d_in[19];
  float* out = (float*)d_out;

  int Kp[3];
  for (int m = 0; m < 3; ++m) {
    const int D = in_sizes[m] / NROWS;
    int k = 256;
    while (k < D) k <<= 1;
    Kp[m] = k;
  }
  const size_t KpSum = (size_t)Kp[0] + Kp[1] + Kp[2];
  const int D0 = in_sizes[0] / NROWS, D1 = in_sizes[1] / NROWS, D2 = in_sizes[2] / NROWS;

  // ---- Workspace layout with lifetime unions (~151 MB total) ----
  const size_t NH = (size_t)NROWS * HID;   // 2M elems
  float* ws = (float*)d_ws;
  // U1: A (encoder out, dead after bn_rownorm) aliases C (gc gemm temp)
  float* A = ws;                                    // 3*NH
  float* C = A;                                     // alias
  float* nval = A + 3 * NH;
  int*   nidx = (int*)(nval + (size_t)3 * NROWS * TOPK);
  float* dinv = (float*)(nidx + (size_t)3 * NROWS * TOPK);
  float* logits = dinv + 3 * NROWS;
  float* fused = logits + (size_t)3 * NROWS * NCLS;
  float* ps    = fused + (size_t)NROWS * NCLS;
  float* ps2   = ps + 3 * 64 * HID;
  float* scale = ps2 + 3 * 64 * HID;
  float* shift = scale + 3 * HID;
  float* M     = shift + 3 * HID;                   // 3*NROWS*64
  float* tauv  = M + (size_t)3 * NROWS * 64;
  int*   gcnt  = (int*)(tauv + 3 * NROWS);
  int*   gidx  = gcnt + 3 * NROWS;                  // 3*NROWS*CAP
  ushort* WhG = (ushort*)(gidx + (size_t)3 * NROWS * CAP);  // 3*HID*HID
  ushort* WlG = WhG + (size_t)3 * HID * HID;
  ushort* WhE = WlG + (size_t)3 * HID * HID;        // HID*KpSum (compact)
  ushort* WlE = WhE + (size_t)HID * KpSum;
  // U3 (big union): enc A-limb planes (dead after enc gemm) overlay
  //                 FN + Ph + Fh + Fl + Hh + Hl
  char* u3 = (char*)(WlE + (size_t)HID * KpSum);
  float* FN = (float*)u3;                           // 3*NH fp32
  ushort* Ph = (ushort*)(FN + 3 * NH);              // 3*NH each below
  ushort* Fh = Ph + 3 * NH;
  ushort* Fl = Fh + 3 * NH;
  ushort* Hh = Fl + 3 * NH;
  ushort* Hl = Hh + 3 * NH;
  ushort* AhE = (ushort*)u3;                        // NROWS*KpSum (compact)
  ushort* AlE = AhE + (size_t)NROWS * KpSum;

  const size_t aOff0 = 0, aOff1 = (size_t)NROWS * Kp[0],
               aOff2 = (size_t)NROWS * (Kp[0] + Kp[1]);
  const size_t wOff0 = 0, wOff1 = (size_t)HID * Kp[0],
               wOff2 = (size_t)HID * (Kp[0] + Kp[1]);

  const dim3 blk(256);
  // Stage 1: encoder (batched over modalities; packAB 4-wide)
  packAB_kernel<<<dim3(((NROWS + HID) * 1024 / 4) / 256, 3), blk, 0, stream>>>(
      x0, x1, x2, eW0, eW1, eW2, AhE, AlE, WhE, WlE,
      D0, D1, D2, Kp[0], Kp[1], Kp[2], aOff0, aOff1, aOff2, wOff0, wOff1, wOff2);
  limbgemm_kernel<true, 1><<<dim3(128, 3), blk, 0, stream>>>(
      AhE, AlE, WhE, WlE, enc_b, A, Kp[0], Kp[1], Kp[2],
      aOff0, aOff1, aOff2, wOff0, wOff1, wOff2);
  // Stage 2: BN + rownorm + limb emit (AhE/AlE dead; FN..Fl live in U3)
  bn_stats_kernel<<<dim3(64, 3), blk, 0, stream>>>(A, ps, ps2);
  bn_finalize_kernel<<<3, blk, 0, stream>>>(ps, ps2, bn_g, bn_b, scale, shift);
  bn_rownorm_kernel<<<dim3(NROWS, 3), blk, 0, stream>>>(A, scale, shift, FN, Ph, Fh, Fl);
  // Stage 3: symmetric stripe-free knn graph (triangular grid, 2080/z,
  // row-major decode, no dead dispatches; BKS=64 single-buffer)
  simtile_kernel<0><<<dim3(2080, 3), dim3(512), 0, stream>>>(Ph, M, nullptr, nullptr, nullptr);
  tau_kernel<<<dim3(NROWS / 4, 3), blk, 0, stream>>>(M, tauv, gcnt);
  simtile_kernel<1><<<dim3(2080, 3), dim3(512), 0, stream>>>(Ph, nullptr, tauv, gcnt, gidx);
  refine_kernel<<<dim3(NROWS / 4, 3), blk, 0, stream>>>(gcnt, gidx, FN, nidx, nval, dinv);
  // Stage 4: gc1 (A dead -> C reuses U1)
  packW_kernel<<<dim3(256, 3), blk, 0, stream>>>(gc1W, WhG, WlG);
  limbgemm_kernel<false, 0><<<dim3(128, 3), blk, 0, stream>>>(
      Fh, Fl, WhG, WlG, nullptr, C, HID, HID, HID,
      0, NH, 2 * NH, 0, (size_t)HID * HID, (size_t)2 * HID * HID);
  spmm_kernel<1><<<dim3(NROWS, 3), blk, 0, stream>>>(C, nidx, nval, dinv, gc1b,
                                                     Hh, Hl, nullptr, nullptr, nullptr);
  // Stage 5: gc2 + fused classifier (h2 never hits HBM)
  packW_kernel<<<dim3(256, 3), blk, 0, stream>>>(gc2W, WhG, WlG);
  limbgemm_kernel<false, 0><<<dim3(128, 3), blk, 0, stream>>>(
      Hh, Hl, WhG, WlG, nullptr, C, HID, HID, HID,
      0, NH, 2 * NH, 0, (size_t)HID * HID, (size_t)2 * HID * HID);
  spmm_kernel<0><<<dim3(NROWS, 3), blk, 0, stream>>>(C, nidx, nval, dinv, gc2b,
                                                     nullptr, nullptr, clfW, clfb, logits);
  // Stage 6: fusion head
  fuse_kernel<<<(NROWS * NCLS + 255) / 256, blk, 0, stream>>>(logits, attn, fused);
  head_kernel<<<NROWS, dim3(128), 0, stream>>>(fused, f1W, f1b, f2W, f2b, out);
}

// Round 13
// 702.949 us; speedup vs baseline: 1.1057x; 1.0562x over previous
//
#include <hip/hip_runtime.h>
#include <cfloat>
#include <cstdint>
#include <cstddef>

#define NROWS 8192
#define HID 256
#define NCLS 5
#define TOPK 10
#define CAP 256     // per-row candidate capacity (typ. ~20-60 used)
#define TM 128
#define TN 128
#define BK 32
#define BKS 64      // sim K-step

typedef __bf16 bf16x8 __attribute__((ext_vector_type(8)));
typedef float f32x4 __attribute__((ext_vector_type(4)));
typedef unsigned short us4 __attribute__((ext_vector_type(4)));

__device__ inline ushort f2bf(float x) {
  unsigned u = __float_as_uint(x);
  unsigned r = (u + 0x7fffu + ((u >> 16) & 1u)) >> 16;  // RNE
  return (ushort)r;
}
__device__ inline float bf2f(ushort b) { return __uint_as_float(((unsigned)b) << 16); }

// async global->LDS 16B/lane; LDS dest is wave-uniform base + lane*16
__device__ __forceinline__ void load_lds16(const void* g, void* l) {
  __builtin_amdgcn_global_load_lds(
      (const __attribute__((address_space(1))) void*)g,
      (__attribute__((address_space(3))) void*)l, 16, 0, 0);
}

// ---------------------------------------------------------------------------
// Batched encoder pack, 4-WIDE (z = modality): X -> hi/lo limb planes
// (COMPACT per-z row stride Kp[z], zero-padded past D), W -> transposed
// [HID x Kp[z]] planes. float4 loads (alignment-guarded) + ushort4 stores;
// per-element RNE math unchanged -> bit-identical values. (R7-verified:
// rest-of-pipeline -44 us vs scalar.)
// ---------------------------------------------------------------------------
__global__ __launch_bounds__(256) void packAB_kernel(const float* __restrict__ X0,
    const float* __restrict__ X1, const float* __restrict__ X2,
    const float* __restrict__ W0, const float* __restrict__ W1,
    const float* __restrict__ W2, ushort* __restrict__ Ah, ushort* __restrict__ Al,
    ushort* __restrict__ Bh, ushort* __restrict__ Bl,
    int D0, int D1, int D2, int Kp0, int Kp1, int Kp2,
    size_t aOff0, size_t aOff1, size_t aOff2,
    size_t wOff0, size_t wOff1, size_t wOff2) {
  const int z = blockIdx.y;
  const float* X = (z == 0) ? X0 : (z == 1) ? X1 : X2;
  const float* W = (z == 0) ? W0 : (z == 1) ? W1 : W2;
  const int D = (z == 0) ? D0 : (z == 1) ? D1 : D2;
  const int Kp = (z == 0) ? Kp0 : (z == 1) ? Kp1 : Kp2;
  const size_t aOff = (z == 0) ? aOff0 : (z == 1) ? aOff1 : aOff2;
  const size_t wOff = (z == 0) ? wOff0 : (z == 1) ? wOff1 : wOff2;
  const int ksh2 = (31 - __clz(Kp)) - 2;     // log2(Kp/4)
  const int id4 = blockIdx.x * 256 + threadIdx.x;
  const int aq = NROWS << ksh2;
  const int wq = HID << ksh2;
  if (id4 >= aq + wq) return;
  float x[4];
  ushort h[4], l[4];
  if (id4 < aq) {
    const int kq = id4 & ((Kp >> 2) - 1);
    const int r = id4 >> ksh2;
    const int k = kq << 2;
    const float* src = X + (size_t)r * D + k;
    if (k + 3 < D && ((((size_t)r * D + k) & 3) == 0)) {
      const float4 v = *(const float4*)src;
      x[0] = v.x; x[1] = v.y; x[2] = v.z; x[3] = v.w;
    } else {
      #pragma unroll
      for (int j = 0; j < 4; ++j) x[j] = (k + j < D) ? src[j] : 0.f;
    }
    #pragma unroll
    for (int j = 0; j < 4; ++j) { h[j] = f2bf(x[j]); l[j] = f2bf(x[j] - bf2f(h[j])); }
    const size_t o = aOff + (((size_t)r) << (ksh2 + 2)) + k;
    *(us4*)&Ah[o] = (us4){h[0], h[1], h[2], h[3]};
    *(us4*)&Al[o] = (us4){l[0], l[1], l[2], l[3]};
  } else {
    const int id2 = id4 - aq;
    const int kq = id2 & ((Kp >> 2) - 1);
    const int n = id2 >> ksh2;
    const int k = kq << 2;
    #pragma unroll
    for (int j = 0; j < 4; ++j) {
      const float xv = (k + j < D) ? W[(size_t)(k + j) * HID + n] : 0.f;
      h[j] = f2bf(xv); l[j] = f2bf(xv - bf2f(h[j]));
    }
    const size_t o = wOff + (((size_t)n) << (ksh2 + 2)) + k;
    *(us4*)&Bh[o] = (us4){h[0], h[1], h[2], h[3]};
    *(us4*)&Bl[o] = (us4){l[0], l[1], l[2], l[3]};
  }
}

// ---------------------------------------------------------------------------
// Batched GCN weight pack: W[z] [HID x HID] -> transposed limb planes.
// ---------------------------------------------------------------------------
__global__ __launch_bounds__(256) void packW_kernel(const float* __restrict__ W,
    ushort* __restrict__ Bh, ushort* __restrict__ Bl) {
  const int z = blockIdx.y;
  const int id = blockIdx.x * 256 + threadIdx.x;  // 65536 per z
  const int k = id >> 8, n = id & 255;
  const size_t wz = (size_t)z * HID * HID;
  const float x = W[wz + (size_t)k * HID + n];
  const ushort h = f2bf(x);
  Bh[wz + (size_t)n * HID + k] = h;
  Bl[wz + (size_t)n * HID + k] = f2bf(x - bf2f(h));
}

// ---------------------------------------------------------------------------
// Batched 3-segment two-limb bf16 MFMA GEMM, 128x128 tile. 4 waves (2x2),
// wave = 64x64 = acc[4][4]. Staging/fragment swizzle = proven R4 mapping.
// 2-PHASE double-buffered staging: step t issues global_load_lds for t+1
// BEFORE computing t; ONE __syncthreads per step (drain overlaps compute).
// Per-k accumulation order (hh,hl,lh) unchanged -> bit-identical results.
// ---------------------------------------------------------------------------
#define STAGE_LIMB(B, K0)                              \
    load_lds16(Ah + a0 + (K0), &AsH[B][p0 * 8]);       \
    load_lds16(Ah + a1 + (K0), &AsH[B][p1 * 8]);       \
    load_lds16(Al + a0 + (K0), &AsL[B][p0 * 8]);       \
    load_lds16(Al + a1 + (K0), &AsL[B][p1 * 8]);       \
    load_lds16(Bh + b0 + (K0), &BsH[B][p0 * 8]);       \
    load_lds16(Bh + b1 + (K0), &BsH[B][p1 * 8]);       \
    load_lds16(Bl + b0 + (K0), &BsL[B][p0 * 8]);       \
    load_lds16(Bl + b1 + (K0), &BsL[B][p1 * 8]);

template<bool BIAS, int ACT>
__global__ __launch_bounds__(256) void limbgemm_kernel(const ushort* __restrict__ Ah,
    const ushort* __restrict__ Al, const ushort* __restrict__ Bh,
    const ushort* __restrict__ Bl, const float* __restrict__ bias,
    float* __restrict__ C, int Kp0, int Kp1, int Kp2,
    size_t aOff0, size_t aOff1, size_t aOff2,
    size_t bOff0, size_t bOff1, size_t bOff2) {
  __shared__ ushort AsH[2][TM * BK], AsL[2][TM * BK], BsH[2][TM * BK], BsL[2][TM * BK];
  const int z = blockIdx.y;
  const int Kp = (z == 0) ? Kp0 : (z == 1) ? Kp1 : Kp2;
  const size_t aO = (z == 0) ? aOff0 : (z == 1) ? aOff1 : aOff2;
  const size_t bO = (z == 0) ? bOff0 : (z == 1) ? bOff1 : bOff2;
  Ah += aO; Al += aO; Bh += bO; Bl += bO;
  C += (size_t)z * NROWS * HID;
  const int tid = threadIdx.x;
  const int wave = tid >> 6, lane = tid & 63;
  // XCD swizzle: 128 blocks = 64 row-blocks x 2 col-blocks
  const int bid = blockIdx.x;
  const int xcd = bid & 7, slot = bid >> 3;      // slot 0..15
  const int bxi = slot & 1;
  const int byi = xcd * 8 + (slot >> 1);
  const int bm = byi * TM, bn = bxi * 128;
  const int wr = (wave >> 1) * 64, wc = (wave & 1) * 64;

  f32x4 acc[4][4];
  const f32x4 zero = {0.f, 0.f, 0.f, 0.f};
  #pragma unroll
  for (int i = 0; i < 4; ++i)
    #pragma unroll
    for (int j = 0; j < 4; ++j) acc[i][j] = zero;

  // staging slots (proven R4 mapping): p in {tid, tid+256}, r=p>>2,
  // kl = (p&3) ^ ((r&3) ^ ((r>>2)&1))
  const int p0 = tid, p1 = tid + 256;
  const int r0 = p0 >> 2, kl0 = (p0 & 3) ^ ((r0 & 3) ^ ((r0 >> 2) & 1));
  const int r1 = p1 >> 2, kl1 = (p1 & 3) ^ ((r1 & 3) ^ ((r1 >> 2) & 1));
  const size_t a0 = (size_t)(bm + r0) * Kp + kl0 * 8;
  const size_t a1 = (size_t)(bm + r1) * Kp + kl1 * 8;
  const size_t b0 = (size_t)(bn + r0) * Kp + kl0 * 8;
  const size_t b1 = (size_t)(bn + r1) * Kp + kl1 * 8;

  // prologue: stage k0=0 into buffer 0
  STAGE_LIMB(0, 0)
  __syncthreads();
  int cur = 0;
  for (int k0 = 0; k0 < Kp; k0 += BK) {
    if (k0 + BK < Kp) {
      STAGE_LIMB(cur ^ 1, k0 + BK)
    }
    bf16x8 ah[4], al[4], bh[4], bl[4];
    const int kg = lane >> 4;
    #pragma unroll
    for (int f = 0; f < 4; ++f) {
      const int m = wr + f * 16 + (lane & 15);
      const int sa = m * 4 + (kg ^ (m & 3) ^ ((m >> 2) & 1));
      ah[f] = *(const bf16x8*)&AsH[cur][sa * 8];
      al[f] = *(const bf16x8*)&AsL[cur][sa * 8];
      const int n = wc + f * 16 + (lane & 15);
      const int sb = n * 4 + (kg ^ (n & 3) ^ ((n >> 2) & 1));
      bh[f] = *(const bf16x8*)&BsH[cur][sb * 8];
      bl[f] = *(const bf16x8*)&BsL[cur][sb * 8];
    }
    #pragma unroll
    for (int fr = 0; fr < 4; ++fr)
      #pragma unroll
      for (int fc = 0; fc < 4; ++fc) {
        acc[fr][fc] = __builtin_amdgcn_mfma_f32_16x16x32_bf16(ah[fr], bh[fc], acc[fr][fc], 0, 0, 0);
        acc[fr][fc] = __builtin_amdgcn_mfma_f32_16x16x32_bf16(ah[fr], bl[fc], acc[fr][fc], 0, 0, 0);
        acc[fr][fc] = __builtin_amdgcn_mfma_f32_16x16x32_bf16(al[fr], bh[fc], acc[fr][fc], 0, 0, 0);
      }
    __syncthreads();
    cur ^= 1;
  }
  const int cq = lane >> 4, cc = lane & 15;
  #pragma unroll
  for (int fr = 0; fr < 4; ++fr) {
    #pragma unroll
    for (int fc = 0; fc < 4; ++fc) {
      const int rb = bm + wr + fr * 16 + cq * 4;
      const int col = bn + wc + fc * 16 + cc;
      const float bb = BIAS ? bias[z * HID + col] : 0.f;
      float* cp = C + (size_t)rb * HID + col;
      #pragma unroll
      for (int e = 0; e < 4; ++e) {
        float v = acc[fr][fc][e] + bb;
        if (ACT == 1) v = fmaxf(v, 0.f);
        cp[(size_t)e * HID] = v;
      }
    }
  }
}

// ---------------------------------------------------------------------------
// Batched coalesced BatchNorm, 3 stages.
// ---------------------------------------------------------------------------
__global__ __launch_bounds__(256) void bn_stats_kernel(const float* __restrict__ F,
    float* __restrict__ ps, float* __restrict__ ps2) {
  const int z = blockIdx.y;
  const int b = blockIdx.x, t = threadIdx.x;
  float s = 0.f, s2 = 0.f;
  const float* p = F + (size_t)z * NROWS * HID + (size_t)b * 128 * HID + t;
  for (int r = 0; r < 128; ++r) {
    const float v = p[(size_t)r * HID];
    s += v; s2 += v * v;
  }
  ps[(size_t)z * 64 * HID + b * HID + t] = s;
  ps2[(size_t)z * 64 * HID + b * HID + t] = s2;
}

__global__ __launch_bounds__(256) void bn_finalize_kernel(const float* __restrict__ ps,
    const float* __restrict__ ps2, const float* __restrict__ g,
    const float* __restrict__ b, float* __restrict__ scale, float* __restrict__ shift) {
  const int z = blockIdx.x;
  const int t = threadIdx.x;
  float s = 0.f, s2 = 0.f;
  for (int i = 0; i < 64; ++i) {
    s += ps[(size_t)z * 64 * HID + i * HID + t];
    s2 += ps2[(size_t)z * 64 * HID + i * HID + t];
  }
  const float mu = s / (float)NROWS;
  const float var = s2 / (float)NROWS - mu * mu;
  const float rstd = rsqrtf(var + 1e-5f);
  const float sc = rstd * g[z * HID + t];
  scale[z * HID + t] = sc;
  shift[z * HID + t] = b[z * HID + t] - mu * sc;
}

// ---------------------------------------------------------------------------
// Batched fused bn-apply + L2 rownorm. Emits FN, Ph (hi-limb fn), Fh/Fl.
// ---------------------------------------------------------------------------
__global__ __launch_bounds__(256) void bn_rownorm_kernel(const float* __restrict__ F,
    const float* __restrict__ scale, const float* __restrict__ shift,
    float* __restrict__ FN, ushort* __restrict__ Ph,
    ushort* __restrict__ Fh, ushort* __restrict__ Fl) {
  const int z = blockIdx.y;
  const int r = blockIdx.x, t = threadIdx.x;
  const size_t zb = (size_t)z * NROWS * HID;
  const float f = F[zb + (size_t)r * HID + t] * scale[z * HID + t] + shift[z * HID + t];
  __shared__ float sh[256];
  sh[t] = f * f;
  __syncthreads();
  for (int st = 128; st > 0; st >>= 1) {
    if (t < st) sh[t] += sh[t + st];
    __syncthreads();
  }
  const float inv = 1.0f / fmaxf(sqrtf(sh[0]), 1e-12f);
  const float fn = f * inv;
  const size_t o = zb + (size_t)r * HID + t;
  FN[o] = fn;
  Ph[o] = f2bf(fn);
  const ushort h = f2bf(f);
  Fh[o] = h;
  Fl[o] = f2bf(f - bf2f(h));
}

// ---------------------------------------------------------------------------
// Batched SYMMETRIC stripe-free sim: TRIANGULAR grid (2080/z, row-major
// decode, no dead dispatches). R6-VERIFIED config: BKS=64 single-buffer,
// 33 KB LDS, m*8+(kgb^(m&7)) swizzle — measured ~117 us, 0 bank conflicts.
// PASS 0: per-row/per-col tile maxes -> M. PASS 1: tau-compaction both dirs.
// ---------------------------------------------------------------------------
template<int PASS>
__global__ __launch_bounds__(512) void simtile_kernel(const ushort* __restrict__ P,
    float* __restrict__ M, const float* __restrict__ tauv,
    int* __restrict__ gcnt, int* __restrict__ gidx) {
  // row-major upper-triangle decode: tlin -> (by, bx) with by <= bx < 64.
  const int tlin = blockIdx.x;
  int by = (int)(64.5f - sqrtf(4160.25f - 2.0f * (float)tlin));
  if (by < 0) by = 0;
  if (by > 63) by = 63;
  while (by > 0 && (by * 64 - (by * (by - 1)) / 2) > tlin) --by;
  while (by < 63 && ((by + 1) * 64 - ((by + 1) * by) / 2) <= tlin) ++by;
  const int bx = by + (tlin - (by * 64 - (by * (by - 1)) / 2));
  const int z = blockIdx.y;
  P += (size_t)z * NROWS * HID;
  if (PASS == 0) M += (size_t)z * NROWS * 64;
  else {
    tauv += (size_t)z * NROWS;
    gcnt += (size_t)z * NROWS;
    gidx += (size_t)z * NROWS * CAP;
  }
  const bool offdiag = (bx != by);
  __shared__ ushort As[TM * BKS];
  __shared__ ushort Bs[TN * BKS];
  __shared__ float Ml[2][TM];
  __shared__ float MlC[4][TN];
  __shared__ float taulA[TM];
  __shared__ float taulB[TN];
  const int tid = threadIdx.x;
  const int wave = tid >> 6, lane = tid & 63;
  const int bm = by * TM;
  const int bn = bx * TN;
  const int wr = (wave >> 1) * 32;
  const int wc = (wave & 1) * 64;

  if (PASS == 1) {
    if (tid < TM) taulA[tid] = tauv[bm + tid];
    else if (tid < TM + TN) taulB[tid - TM] = tauv[bn + (tid - TM)];
  }

  const ushort* pa[2];
  const ushort* pb[2];
  #pragma unroll
  for (int j = 0; j < 2; ++j) {
    const int s = tid + j * 512;
    const int m = s >> 3;
    const int kg = (s & 7) ^ (m & 7);
    pa[j] = P + (size_t)(bm + m) * HID + kg * 8;
    pb[j] = P + (size_t)(bn + m) * HID + kg * 8;
  }

  f32x4 acc[2][4];
  const f32x4 zero = {0.f, 0.f, 0.f, 0.f};
  #pragma unroll
  for (int i = 0; i < 2; ++i)
    #pragma unroll
    for (int j = 0; j < 4; ++j) acc[i][j] = zero;

  for (int k0 = 0; k0 < HID; k0 += BKS) {
    __syncthreads();
    #pragma unroll
    for (int j = 0; j < 2; ++j) {
      load_lds16(pa[j] + k0, &As[(tid + j * 512) * 8]);
      load_lds16(pb[j] + k0, &Bs[(tid + j * 512) * 8]);
    }
    __syncthreads();
    #pragma unroll
    for (int h = 0; h < 2; ++h) {
      const int kgb = h * 4 + (lane >> 4);
      bf16x8 af[2], bf[4];
      #pragma unroll
      for (int f = 0; f < 2; ++f) {
        const int m = wr + f * 16 + (lane & 15);
        const int sa = m * 8 + (kgb ^ (m & 7));
        af[f] = *(const bf16x8*)&As[sa * 8];
      }
      #pragma unroll
      for (int f = 0; f < 4; ++f) {
        const int n = wc + f * 16 + (lane & 15);
        const int sb = n * 8 + (kgb ^ (n & 7));
        bf[f] = *(const bf16x8*)&Bs[sb * 8];
      }
      #pragma unroll
      for (int fr = 0; fr < 2; ++fr)
        #pragma unroll
        for (int fc = 0; fc < 4; ++fc)
          acc[fr][fc] = __builtin_amdgcn_mfma_f32_16x16x32_bf16(af[fr], bf[fc], acc[fr][fc], 0, 0, 0);
    }
  }

  const int cq = lane >> 4, cc = lane & 15;
  if (PASS == 0) {
    #pragma unroll
    for (int fr = 0; fr < 2; ++fr) {
      #pragma unroll
      for (int e = 0; e < 4; ++e) {
        const int lrow = wr + fr * 16 + cq * 4 + e;
        const int grow = bm + lrow;
        float mx = -FLT_MAX;
        #pragma unroll
        for (int fc = 0; fc < 4; ++fc) {
          const int col = bn + wc + fc * 16 + cc;
          mx = fmaxf(mx, (col == grow) ? -FLT_MAX : acc[fr][fc][e]);
        }
        #pragma unroll
        for (int s = 1; s < 16; s <<= 1) mx = fmaxf(mx, __shfl_xor(mx, s));
        if (cc == 0) Ml[wave & 1][lrow] = mx;
      }
    }
    if (offdiag) {
      #pragma unroll
      for (int fc = 0; fc < 4; ++fc) {
        float mx = -FLT_MAX;
        #pragma unroll
        for (int fr = 0; fr < 2; ++fr)
          #pragma unroll
          for (int e = 0; e < 4; ++e) mx = fmaxf(mx, acc[fr][fc][e]);
        mx = fmaxf(mx, __shfl_xor(mx, 16));
        mx = fmaxf(mx, __shfl_xor(mx, 32));
        if (cq == 0) MlC[wave >> 1][wc + fc * 16 + cc] = mx;
      }
    }
    __syncthreads();
    if (tid < TM) M[(size_t)(bm + tid) * 64 + bx] = fmaxf(Ml[0][tid], Ml[1][tid]);
    if (offdiag && tid < TN) {
      const float mx = fmaxf(fmaxf(MlC[0][tid], MlC[1][tid]),
                             fmaxf(MlC[2][tid], MlC[3][tid]));
      M[(size_t)(bn + tid) * 64 + by] = mx;
    }
  } else {
    __syncthreads();
    #pragma unroll
    for (int fr = 0; fr < 2; ++fr) {
      #pragma unroll
      for (int e = 0; e < 4; ++e) {
        const int lrow = wr + fr * 16 + cq * 4 + e;
        const int grow = bm + lrow;
        const float tA = taulA[lrow];
        #pragma unroll
        for (int fc = 0; fc < 4; ++fc) {
          const int lcol = wc + fc * 16 + cc;
          const int gcol = bn + lcol;
          const float v = acc[fr][fc][e];
          if (gcol != grow && v >= tA) {
            const int pos = atomicAdd(&gcnt[grow], 1);
            if (pos < CAP) gidx[(size_t)grow * CAP + pos] = gcol;
          }
          if (offdiag && v >= taulB[lcol]) {
            const int pos = atomicAdd(&gcnt[gcol], 1);
            if (pos < CAP) gidx[(size_t)gcol * CAP + pos] = grow;
          }
        }
      }
    }
  }
}

// ---------------------------------------------------------------------------
// Batched tau: tau[row] = 16th largest of 64 tile-maxes; zeroes gcnt.
// ---------------------------------------------------------------------------
__global__ __launch_bounds__(256) void tau_kernel(const float* __restrict__ M,
    float* __restrict__ tauv, int* __restrict__ gcnt) {
  const int z = blockIdx.y;
  const int wave = threadIdx.x >> 6, lane = threadIdx.x & 63;
  const int row = blockIdx.x * 4 + wave;
  float cur = M[(size_t)z * NROWS * 64 + (size_t)row * 64 + lane];
  float tau = cur;
  #pragma unroll
  for (int sel = 0; sel < 16; ++sel) {
    float bv = cur;
    int bl = lane;
    #pragma unroll
    for (int s = 1; s < 64; s <<= 1) {
      const float ov = __shfl_xor(bv, s);
      const int ol = __shfl_xor(bl, s);
      if (ov > bv || (ov == bv && ol < bl)) { bv = ov; bl = ol; }
    }
    tau = bv;
    if (lane == bl) cur = -FLT_MAX;
  }
  if (lane == 0) {
    tauv[(size_t)z * NROWS + row] = tau;
    gcnt[(size_t)z * NROWS + row] = 0;
  }
}

// ---------------------------------------------------------------------------
// Batched exact refinement: fp32 dots for all candidates, exact top-10.
// R12-verified: LOAD-BALANCED chunk scheduling — 4 rows/block, 4 waves share
// the block's flattened chunk list (prefix-sum over ceil(cnt_i/16)).
// Per-chunk dot = identical 64-fmaf chain + shfl reduce -> bit-identical.
// ---------------------------------------------------------------------------
__global__ __launch_bounds__(256) void refine_kernel(const int* __restrict__ gcnt,
    const int* __restrict__ gidx, const float* __restrict__ FN,
    int* __restrict__ nidx, float* __restrict__ nval, float* __restrict__ dinv) {
  const int z = blockIdx.y;
  gcnt += (size_t)z * NROWS;
  gidx += (size_t)z * NROWS * CAP;
  FN += (size_t)z * NROWS * HID;
  nidx += (size_t)z * NROWS * TOPK;
  nval += (size_t)z * NROWS * TOPK;
  dinv += (size_t)z * NROWS;
  const int wave = threadIdx.x >> 6, lane = threadIdx.x & 63;
  const int rbase = blockIdx.x * 4;
  int cnt4[4], pre[5];
  pre[0] = 0;
  #pragma unroll
  for (int i = 0; i < 4; ++i) {
    cnt4[i] = min(gcnt[rbase + i], CAP);
    pre[i + 1] = pre[i] + ((cnt4[i] + 15) >> 4);
  }
  const int total = pre[4];
  __shared__ float fnrow[4][4 * 68];   // padded: 4 segments x 68 floats
  __shared__ float ev[4][CAP];
  {
    const float4 v = ((const float4*)(FN + (size_t)(rbase + wave) * HID))[lane];
    const int seg = lane >> 4, pos = (lane & 15) * 4;
    *(float4*)&fnrow[wave][seg * 68 + pos] = v;
  }
  __syncthreads();
  const int c = lane >> 2, q4 = lane & 3;
  for (int j = wave; j < total; j += 4) {
    int i = 0;
    while (j >= pre[i + 1]) ++i;       // wave-uniform scan, i in 0..3
    const int row = rbase + i;
    const int cnt = cnt4[i];
    const int b0 = (j - pre[i]) * 16;
    const int ci = b0 + c;
    const int cand = (ci < cnt) ? gidx[(size_t)row * CAP + ci] : 0;
    const float4* frp = (const float4*)&fnrow[i][q4 * 68];
    const float4* fcp = (const float4*)(FN + (size_t)cand * HID + q4 * 64);
    float s = 0.f;
    #pragma unroll
    for (int kk = 0; kk < 16; ++kk) {
      const float4 a = frp[kk];
      const float4 b = fcp[kk];
      s = fmaf(a.x, b.x, s);
      s = fmaf(a.y, b.y, s);
      s = fmaf(a.z, b.z, s);
      s = fmaf(a.w, b.w, s);
    }
    s += __shfl_xor(s, 1);
    s += __shfl_xor(s, 2);
    if (q4 == 0 && ci < cnt) ev[i][ci] = s;
  }
  __syncthreads();
  // selection: wave i handles row i (R9-identical)
  const int row = rbase + wave;
  const int cnt = cnt4[wave];
  float outv[TOPK];
  int outi[TOPK];
  float sum = 1.0f;  // diag contributes 1
  #pragma unroll
  for (int sel = 0; sel < TOPK; ++sel) {
    float bv = -FLT_MAX;
    int bp = 0;
    #pragma unroll
    for (int j = 0; j < 4; ++j) {
      const int p = lane + j * 64;
      if (p < cnt) {
        const float v = ev[wave][p];
        if (v > bv) { bv = v; bp = p; }
      }
    }
    #pragma unroll
    for (int s = 1; s < 64; s <<= 1) {
      const float ov = __shfl_xor(bv, s);
      const int op = __shfl_xor(bp, s);
      if (ov > bv || (ov == bv && op < bp)) { bv = ov; bp = op; }
    }
    outv[sel] = bv;
    outi[sel] = bp;
    sum += fabsf(bv);
    if (lane == 0) ev[wave][bp] = -FLT_MAX;
  }
  if (lane == 0) {
    const float inv = 1.0f / fmaxf(sum, 1e-12f);
    dinv[row] = inv;
    #pragma unroll
    for (int sel = 0; sel < TOPK; ++sel) {
      nval[row * TOPK + sel] = outv[sel] * inv;
      nidx[row * TOPK + sel] = gidx[(size_t)row * CAP + outi[sel]];
    }
  }
}

// ---------------------------------------------------------------------------
// Batched sparse adj (11 nnz/row) @ T + bias, leaky_relu(0.25).
// R13: MLP HOIST — all 10 (nidx,nval) pairs loaded first, then all 10
// gathered T-rows issued as independent loads (breaks the idx-load ->
// row-load serial chain), then accumulate in the SAME ascending order ->
// bit-identical results.
// EMIT=1: write two-limb bf16 planes. EMIT=0: fused classifier epilogue.
// ---------------------------------------------------------------------------
template<int EMIT>
__global__ __launch_bounds__(256) void spmm_kernel(const float* __restrict__ T,
    const int* __restrict__ nidx, const float* __restrict__ nval,
    const float* __restrict__ dinv, const float* __restrict__ bias,
    ushort* __restrict__ Hh, ushort* __restrict__ Hl,
    const float* __restrict__ clfW, const float* __restrict__ clfb,
    float* __restrict__ L) {
  const int z = blockIdx.y;
  const size_t zb = (size_t)z * NROWS * HID;
  T += zb;
  nidx += (size_t)z * NROWS * TOPK;
  nval += (size_t)z * NROWS * TOPK;
  dinv += (size_t)z * NROWS;
  const int r = blockIdx.x, c = threadIdx.x;
  int idxv[TOPK];
  float wv[TOPK];
  #pragma unroll
  for (int n = 0; n < TOPK; ++n) {
    idxv[n] = nidx[r * TOPK + n];
    wv[n] = nval[r * TOPK + n];
  }
  const float dv = dinv[r];
  const float t0 = T[(size_t)r * HID + c];
  float tv[TOPK];
  #pragma unroll
  for (int n = 0; n < TOPK; ++n) tv[n] = T[(size_t)idxv[n] * HID + c];
  float acc = dv * t0;
  #pragma unroll
  for (int n = 0; n < TOPK; ++n) acc += wv[n] * tv[n];
  acc += bias[z * HID + c];
  const float v = acc >= 0.f ? acc : 0.25f * acc;
  if (EMIT == 1) {
    const size_t o = zb + (size_t)r * HID + c;
    const ushort h = f2bf(v);
    Hh[o] = h;
    Hl[o] = f2bf(v - bf2f(h));
  } else {
    // fused classifier: logits[r][cls] = sum_c v[c] * W[c][cls] + b[cls]
    __shared__ float wsum[4][NCLS];
    const int wave = c >> 6, lane = c & 63;
    const float* wrow = clfW + (size_t)z * HID * NCLS + (size_t)c * NCLS;
    #pragma unroll
    for (int cls = 0; cls < NCLS; ++cls) {
      float p = v * wrow[cls];
      #pragma unroll
      for (int s = 1; s < 64; s <<= 1) p += __shfl_xor(p, s);
      if (lane == 0) wsum[wave][cls] = p;
    }
    __syncthreads();
    if (c < NCLS) {
      const float lg = clfb[z * NCLS + c] + wsum[0][c] + wsum[1][c] + wsum[2][c] + wsum[3][c];
      L[(size_t)z * NROWS * NCLS + (size_t)r * NCLS + c] = lg;
    }
  }
}

// ---------------------------------------------------------------------------
// R13: merged fusion + head (one kernel; the 5 fused values computed inline
// by threads 0..4 with the EXACT same expressions as the old fuse_kernel ->
// bit-identical; saves a launch + the fused[] HBM round trip).
// ---------------------------------------------------------------------------
__global__ __launch_bounds__(128) void fusehead_kernel(const float* __restrict__ L,
    const float* __restrict__ attn,
    const float* __restrict__ W1, const float* __restrict__ b1,
    const float* __restrict__ W2, const float* __restrict__ b2,
    float* __restrict__ out) {
  const int r = blockIdx.x, t = threadIdx.x;
  __shared__ float f[NCLS];
  __shared__ float hh[128];
  if (t < NCLS) {
    const int id = r * NCLS + t;
    const float a0 = attn[0], a1 = attn[1], a2 = attn[2];
    const float m = fmaxf(a0, fmaxf(a1, a2));
    const float e0 = expf(a0 - m), e1 = expf(a1 - m), e2 = expf(a2 - m);
    const float inv = 1.0f / (e0 + e1 + e2);
    const float l0 = L[id];
    const float l1 = L[NROWS * NCLS + id];
    const float l2 = L[2 * NROWS * NCLS + id];
    const float s0 = 1.0f / (1.0f + expf(-l0));
    const float s1 = 1.0f / (1.0f + expf(-l1));
    const float s2 = 1.0f / (1.0f + expf(-l2));
    f[t] = (e0 * s0 + e1 * s1 + e2 * s2) * inv;
  }
  __syncthreads();
  float s = b1[t];
  #pragma unroll
  for (int k = 0; k < NCLS; ++k) s += f[k] * W1[k * 128 + t];
  hh[t] = s >= 0.f ? s : 0.25f * s;
  __syncthreads();
  if (t < NCLS) {
    float o = b2[t];
    for (int k = 0; k < 128; ++k) o += hh[k] * W2[k * NCLS + t];
    out[r * NCLS + t] = o;
  }
}

// ---------------------------------------------------------------------------
extern "C" void kernel_launch(void* const* d_in, const int* in_sizes, int n_in,
                              void* d_out, int out_size, void* d_ws, size_t ws_size,
                              hipStream_t stream) {
  const float* x0 = (const float*)d_in[0];
  const float* x1 = (const float*)d_in[1];
  const float* x2 = (const float*)d_in[2];
  const float* eW0 = (const float*)d_in[3];
  const float* eW1 = (const float*)d_in[4];
  const float* eW2 = (const float*)d_in[5];
  const float* enc_b = (const float*)d_in[6];
  const float* bn_g  = (const float*)d_in[7];
  const float* bn_b  = (const float*)d_in[8];
  const float* gc1W  = (const float*)d_in[9];
  const float* gc1b  = (const float*)d_in[10];
  const float* gc2W  = (const float*)d_in[11];
  const float* gc2b  = (const float*)d_in[12];
  const float* clfW  = (const float*)d_in[13];
  const float* clfb  = (const float*)d_in[14];
  const float* attn  = (const float*)d_in[15];
  const float* f1W   = (const float*)d_in[16];
  const float* f1b   = (const float*)d_in[17];
  const float* f2W   = (const float*)d_in[18];
  const float* f2b   = (const float*)d_in[19];
  float* out = (float*)d_out;

  int Kp[3];
  for (int m = 0; m < 3; ++m) {
    const int D = in_sizes[m] / NROWS;
    int k = 256;
    while (k < D) k <<= 1;
    Kp[m] = k;
  }
  const size_t KpSum = (size_t)Kp[0] + Kp[1] + Kp[2];
  const int D0 = in_sizes[0] / NROWS, D1 = in_sizes[1] / NROWS, D2 = in_sizes[2] / NROWS;

  // ---- Workspace layout with lifetime unions (~151 MB total) ----
  const size_t NH = (size_t)NROWS * HID;   // 2M elems
  float* ws = (float*)d_ws;
  // U1: A (encoder out, dead after bn_rownorm) aliases C (gc gemm temp)
  float* A = ws;                                    // 3*NH
  float* C = A;                                     // alias
  float* nval = A + 3 * NH;
  int*   nidx = (int*)(nval + (size_t)3 * NROWS * TOPK);
  float* dinv = (float*)(nidx + (size_t)3 * NROWS * TOPK);
  float* logits = dinv + 3 * NROWS;
  float* fused = logits + (size_t)3 * NROWS * NCLS;
  float* ps    = fused + (size_t)NROWS * NCLS;
  float* ps2   = ps + 3 * 64 * HID;
  float* scale = ps2 + 3 * 64 * HID;
  float* shift = scale + 3 * HID;
  float* M     = shift + 3 * HID;                   // 3*NROWS*64
  float* tauv  = M + (size_t)3 * NROWS * 64;
  int*   gcnt  = (int*)(tauv + 3 * NROWS);
  int*   gidx  = gcnt + 3 * NROWS;                  // 3*NROWS*CAP
  ushort* WhG = (ushort*)(gidx + (size_t)3 * NROWS * CAP);  // 3*HID*HID
  ushort* WlG = WhG + (size_t)3 * HID * HID;
  ushort* WhE = WlG + (size_t)3 * HID * HID;        // HID*KpSum (compact)
  ushort* WlE = WhE + (size_t)HID * KpSum;
  // U3 (big union): enc A-limb planes (dead after enc gemm) overlay
  //                 FN + Ph + Fh + Fl + Hh + Hl
  char* u3 = (char*)(WlE + (size_t)HID * KpSum);
  float* FN = (float*)u3;                           // 3*NH fp32
  ushort* Ph = (ushort*)(FN + 3 * NH);              // 3*NH each below
  ushort* Fh = Ph + 3 * NH;
  ushort* Fl = Fh + 3 * NH;
  ushort* Hh = Fl + 3 * NH;
  ushort* Hl = Hh + 3 * NH;
  ushort* AhE = (ushort*)u3;                        // NROWS*KpSum (compact)
  ushort* AlE = AhE + (size_t)NROWS * KpSum;

  const size_t aOff0 = 0, aOff1 = (size_t)NROWS * Kp[0],
               aOff2 = (size_t)NROWS * (Kp[0] + Kp[1]);
  const size_t wOff0 = 0, wOff1 = (size_t)HID * Kp[0],
               wOff2 = (size_t)HID * (Kp[0] + Kp[1]);

  const dim3 blk(256);
  // Stage 1: encoder (batched over modalities; packAB 4-wide)
  packAB_kernel<<<dim3(((NROWS + HID) * 1024 / 4) / 256, 3), blk, 0, stream>>>(
      x0, x1, x2, eW0, eW1, eW2, AhE, AlE, WhE, WlE,
      D0, D1, D2, Kp[0], Kp[1], Kp[2], aOff0, aOff1, aOff2, wOff0, wOff1, wOff2);
  limbgemm_kernel<true, 1><<<dim3(128, 3), blk, 0, stream>>>(
      AhE, AlE, WhE, WlE, enc_b, A, Kp[0], Kp[1], Kp[2],
      aOff0, aOff1, aOff2, wOff0, wOff1, wOff2);
  // Stage 2: BN + rownorm + limb emit (AhE/AlE dead; FN..Fl live in U3)
  bn_stats_kernel<<<dim3(64, 3), blk, 0, stream>>>(A, ps, ps2);
  bn_finalize_kernel<<<3, blk, 0, stream>>>(ps, ps2, bn_g, bn_b, scale, shift);
  bn_rownorm_kernel<<<dim3(NROWS, 3), blk, 0, stream>>>(A, scale, shift, FN, Ph, Fh, Fl);
  // Stage 3: symmetric stripe-free knn graph (triangular grid, 2080/z,
  // row-major decode, no dead dispatches; BKS=64 single-buffer)
  simtile_kernel<0><<<dim3(2080, 3), dim3(512), 0, stream>>>(Ph, M, nullptr, nullptr, nullptr);
  tau_kernel<<<dim3(NROWS / 4, 3), blk, 0, stream>>>(M, tauv, gcnt);
  simtile_kernel<1><<<dim3(2080, 3), dim3(512), 0, stream>>>(Ph, nullptr, tauv, gcnt, gidx);
  refine_kernel<<<dim3(NROWS / 4, 3), blk, 0, stream>>>(gcnt, gidx, FN, nidx, nval, dinv);
  // Stage 4: gc1 (A dead -> C reuses U1)
  packW_kernel<<<dim3(256, 3), blk, 0, stream>>>(gc1W, WhG, WlG);
  limbgemm_kernel<false, 0><<<dim3(128, 3), blk, 0, stream>>>(
      Fh, Fl, WhG, WlG, nullptr, C, HID, HID, HID,
      0, NH, 2 * NH, 0, (size_t)HID * HID, (size_t)2 * HID * HID);
  spmm_kernel<1><<<dim3(NROWS, 3), blk, 0, stream>>>(C, nidx, nval, dinv, gc1b,
                                                     Hh, Hl, nullptr, nullptr, nullptr);
  // Stage 5: gc2 + fused classifier (h2 never hits HBM)
  packW_kernel<<<dim3(256, 3), blk, 0, stream>>>(gc2W, WhG, WlG);
  limbgemm_kernel<false, 0><<<dim3(128, 3), blk, 0, stream>>>(
      Hh, Hl, WhG, WlG, nullptr, C, HID, HID, HID,
      0, NH, 2 * NH, 0, (size_t)HID * HID, (size_t)2 * HID * HID);
  spmm_kernel<0><<<dim3(NROWS, 3), blk, 0, stream>>>(C, nidx, nval, dinv, gc2b,
                                                     nullptr, nullptr, clfW, clfb, logits);
  // Stage 6: merged fusion + head
  fusehead_kernel<<<NROWS, dim3(128), 0, stream>>>(logits, attn, f1W, f1b, f2W, f2b, out);
}